// Round 4
// baseline (354.977 us; speedup 1.0000x reference)
//
#include <hip/hip_runtime.h>
#include <hip/hip_bf16.h>
#include <stdint.h>

typedef __attribute__((ext_vector_type(8))) short short8;
typedef __attribute__((ext_vector_type(4))) short short4v;
typedef __attribute__((ext_vector_type(4))) float f32x4;

#define LSEQ 4096
#define DMODEL 1024
#define NHEAD 8
#define HDIM 128
#define MTOT 8192
#define NQKV 3072

__device__ __forceinline__ unsigned short f2bf(float f){
  unsigned u = __float_as_uint(f);
  u += 0x7fffu + ((u >> 16) & 1u);
  return (unsigned short)(u >> 16);
}
__device__ __forceinline__ float bf2f(unsigned short h){
  return __uint_as_float(((unsigned)h) << 16);
}

typedef const __attribute__((address_space(1))) void* gas_ptr;
typedef __attribute__((address_space(3))) void* las_ptr;
__device__ __forceinline__ void gload_lds16(const void* g, void* l){
  __builtin_amdgcn_global_load_lds((gas_ptr)(uintptr_t)g,
                                   (las_ptr)(unsigned)(uintptr_t)l, 16, 0, 0);
}

// ---------------- fp32 -> bf16 cast (8 elems/thread) ----------------
__global__ __launch_bounds__(256) void k_cvt(const float* __restrict__ in,
                                             unsigned short* __restrict__ out, int n8){
  int i = blockIdx.x*256 + threadIdx.x;
  if (i >= n8) return;
  const float4* p = (const float4*)in + (size_t)i*2;
  float4 a = p[0], b = p[1];
  short8 r;
  r[0]=(short)f2bf(a.x); r[1]=(short)f2bf(a.y); r[2]=(short)f2bf(a.z); r[3]=(short)f2bf(a.w);
  r[4]=(short)f2bf(b.x); r[5]=(short)f2bf(b.y); r[6]=(short)f2bf(b.z); r[7]=(short)f2bf(b.w);
  *(short8*)(out + (size_t)i*8) = r;
}

// ---------------- fp32 [R][C] -> bf16 transposed [C][R] ----------------
__global__ __launch_bounds__(256) void k_transpose_cvt(const float* __restrict__ in,
                                                       unsigned short* __restrict__ out,
                                                       int R, int C){
  __shared__ unsigned short tile[32][33];
  int c0 = blockIdx.x*32, r0 = blockIdx.y*32;
  int tx = threadIdx.x & 31, ty = threadIdx.x >> 5;   // 32 x 8
  #pragma unroll
  for (int i=0;i<32;i+=8)
    tile[ty+i][tx] = f2bf(in[(size_t)(r0+ty+i)*C + c0+tx]);
  __syncthreads();
  #pragma unroll
  for (int i=0;i<32;i+=8)
    out[(size_t)(c0+ty+i)*R + r0+tx] = tile[tx][ty+i];
}

// ---------------- bf16 GEMM: C[M][N] = A[M][K] * Bt[N][K]^T + bias ----------------
template<int OUT_BF16>
__global__ __launch_bounds__(256) void k_gemm_bt(const unsigned short* __restrict__ A,
                                                 const unsigned short* __restrict__ Bt,
                                                 const float* __restrict__ bias,
                                                 void* __restrict__ Cout,
                                                 int M, int N, int K){
  __shared__ unsigned short As[128*64];
  __shared__ unsigned short Bs[128*64];
  int tid = threadIdx.x, lane = tid & 63, wave = tid >> 6;
  int wm = wave >> 1, wn = wave & 1;
  int m0 = blockIdx.y*128, n0 = blockIdx.x*128;
  f32x4 zero = {0.f,0.f,0.f,0.f};
  f32x4 acc[4][4];
  #pragma unroll
  for (int mi=0;mi<4;++mi)
    #pragma unroll
    for (int ni=0;ni<4;++ni) acc[mi][ni] = zero;

  int srow = lane >> 3;
  int soffb = (lane & 7) * 16;
  int scol = (soffb ^ (srow << 4)) >> 1;
  int cg = lane >> 4, cl = lane & 15;

  int nkt = K >> 6;
  for (int kt = 0; kt < nkt; ++kt){
    if (kt) __syncthreads();
    int kbase = kt*64;
    #pragma unroll
    for (int j=0;j<4;++j){
      int ch = wave*4 + j;
      int row = ch*8 + srow;
      gload_lds16(A  + (size_t)(m0+row)*K + kbase + scol, (char*)As + ch*1024);
      gload_lds16(Bt + (size_t)(n0+row)*K + kbase + scol, (char*)Bs + ch*1024);
    }
    __syncthreads();

    short8 af[4][2], bf[4][2];
    #pragma unroll
    for (int mi=0;mi<4;++mi){
      int row = wm*64 + mi*16 + cl;
      int key = (row & 7) << 4;
      #pragma unroll
      for (int kk=0;kk<2;++kk)
        af[mi][kk] = *(const short8*)((const char*)As + row*128 + ((kk*64 + cg*16) ^ key));
    }
    #pragma unroll
    for (int ni=0;ni<4;++ni){
      int row = wn*64 + ni*16 + cl;
      int key = (row & 7) << 4;
      #pragma unroll
      for (int kk=0;kk<2;++kk)
        bf[ni][kk] = *(const short8*)((const char*)Bs + row*128 + ((kk*64 + cg*16) ^ key));
    }
    #pragma unroll
    for (int kk=0;kk<2;++kk)
      #pragma unroll
      for (int mi=0;mi<4;++mi)
        #pragma unroll
        for (int ni=0;ni<4;++ni)
          acc[mi][ni] = __builtin_amdgcn_mfma_f32_16x16x32_bf16(af[mi][kk], bf[ni][kk], acc[mi][ni], 0,0,0);
  }

  #pragma unroll
  for (int ni=0;ni<4;++ni){
    int col = n0 + wn*64 + ni*16 + cl;
    float bv = bias[col];
    #pragma unroll
    for (int mi=0;mi<4;++mi){
      int r = m0 + wm*64 + mi*16 + cg*4;
      #pragma unroll
      for (int i=0;i<4;++i){
        float v = acc[mi][ni][i] + bv;
        if (OUT_BF16) ((unsigned short*)Cout)[(size_t)(r+i)*N + col] = f2bf(v);
        else          ((float*)Cout)[(size_t)(r+i)*N + col] = v;
      }
    }
  }
}

// ---------------- fused RMSNorm(q,k) + interleaved RoPE ----------------
__global__ __launch_bounds__(256) void k_norm_rope(unsigned short* __restrict__ qkv,
                                                   const float* __restrict__ fcos,
                                                   const float* __restrict__ fsin,
                                                   const float* __restrict__ gq,
                                                   const float* __restrict__ gk){
  int bl = blockIdx.x;
  int l = bl & (LSEQ-1);
  int t = threadIdx.x;
  unsigned short* row = qkv + (size_t)bl * NQKV;
  int d0 = t*4;
  short4v qv = *(short4v*)(row + d0);
  short4v kv = *(short4v*)(row + DMODEL + d0);
  float q[4], k[4];
  #pragma unroll
  for (int j=0;j<4;++j){ q[j] = bf2f((unsigned short)qv[j]); k[j] = bf2f((unsigned short)kv[j]); }
  float sq = q[0]*q[0]+q[1]*q[1]+q[2]*q[2]+q[3]*q[3];
  float sk = k[0]*k[0]+k[1]*k[1]+k[2]*k[2]+k[3]*k[3];
  #pragma unroll
  for (int o=32;o;o>>=1){ sq += __shfl_xor(sq,o); sk += __shfl_xor(sk,o); }
  __shared__ float red[8];
  int lane = t & 63, wv = t >> 6;
  if (!lane){ red[wv] = sq; red[4+wv] = sk; }
  __syncthreads();
  sq = red[0]+red[1]+red[2]+red[3];
  sk = red[4]+red[5]+red[6]+red[7];
  float rq = rsqrtf(sq*(1.f/1024.f) + 1e-6f);
  float rk = rsqrtf(sk*(1.f/1024.f) + 1e-6f);
  int hd = d0 & (HDIM-1);
  int fi = (l << 6) + (hd >> 1);
  float c0 = fcos[fi], s0 = fsin[fi], c1 = fcos[fi+1], s1 = fsin[fi+1];
  {
    float x1 = q[0]*rq*gq[d0],   x2 = q[1]*rq*gq[d0+1];
    float x3 = q[2]*rq*gq[d0+2], x4 = q[3]*rq*gq[d0+3];
    short4v qo;
    qo[0]=(short)f2bf(x1*c0 - x2*s0); qo[1]=(short)f2bf(x1*s0 + x2*c0);
    qo[2]=(short)f2bf(x3*c1 - x4*s1); qo[3]=(short)f2bf(x3*s1 + x4*c1);
    *(short4v*)(row + d0) = qo;
  }
  {
    float x1 = k[0]*rk*gk[d0],   x2 = k[1]*rk*gk[d0+1];
    float x3 = k[2]*rk*gk[d0+2], x4 = k[3]*rk*gk[d0+3];
    short4v ko;
    ko[0]=(short)f2bf(x1*c0 - x2*s0); ko[1]=(short)f2bf(x1*s0 + x2*c0);
    ko[2]=(short)f2bf(x3*c1 - x4*s1); ko[3]=(short)f2bf(x3*s1 + x4*c1);
    *(short4v*)(row + DMODEL + d0) = ko;
  }
}

// ---------------- flash attention v4: 8 waves x 16 q-rows, KVBLK=128,
// swapped QK^T, exp2 softmax + defer-max, V via gload_lds + ds_read_b64_tr_b16 ----
union V8u { short8 v; struct { short4v lo, hi; } s; };

__global__ __launch_bounds__(512, 4) void k_attn(const unsigned short* __restrict__ qkv,
                                                 unsigned short* __restrict__ o){
  __shared__ __align__(128) unsigned short Ks[128*128];   // 32KB, rows 256B, XOR-swizzled
  __shared__ __align__(128) unsigned short Vs[128*128];   // 32KB, [dblk8][kv4 32][4][16]
  __shared__ __align__(128) unsigned short Ps[8][16*64];  // 16KB, per-wave P bridge
  int bh = blockIdx.y; int b = bh >> 3, h = bh & 7;
  int q0 = blockIdx.x * 128;
  int tid = threadIdx.x, lane = tid & 63, wave = tid >> 6;
  int cg = lane >> 4, cl = lane & 15;
  const unsigned short* base = qkv + (size_t)b*LSEQ*NQKV + h*HDIM;
  const unsigned short* kgl = base + DMODEL;
  const unsigned short* vgl = base + 2*DMODEL;

  // Q fragments (B-operand of swapped QK^T): Q[q=cl][d=kkq*32+cg*8+e]
  short8 qf[4];
  {
    const unsigned short* qr = base + (size_t)(q0 + wave*16 + cl)*NQKV;
    #pragma unroll
    for (int kk=0;kk<4;++kk) qf[kk] = *(const short8*)(qr + kk*32 + cg*8);
  }

  // V staging source decode (chunk c2 = dblk*4 + kvh): lane -> (kv, d)
  int v_kv = (lane>>3)*4 + ((lane&7)>>1);   // + kvh*32
  int v_d  = (lane&1)*8;                    // + dblk*16

  const float K2 = 0.12753568849800323f;    // (1/sqrt(128)) * log2(e)
  float mrow = -3.0e38f, lrow = 0.f;
  f32x4 zero = {0.f,0.f,0.f,0.f};
  f32x4 accO[8];
  #pragma unroll
  for (int dt=0;dt<8;++dt) accO[dt] = zero;

  unsigned short* pw = &Ps[wave][0];
  int keyc = (cl & 7) << 3;                 // element XOR key for P bridge
  int keyk = (cl & 7) << 4;                 // byte XOR key for K reads
  // tr-read base: column = cl (addr step 8B/col), + cg's 2-block offset
  unsigned vbase = (unsigned)(uintptr_t)&Vs[0] + (unsigned)(cg*256 + cl*8);

  for (int kv0 = 0; kv0 < LSEQ; kv0 += 128){
    if (kv0) __syncthreads();
    // ---- stage K (4 chunks/wave), pre-swizzled source ----
    #pragma unroll
    for (int j=0;j<4;++j){
      int ch = wave*4 + j;                  // 32 chunks, 4 rows each
      int row = ch*4 + cg;
      int srcb = (cl*16) ^ ((row & 7) << 4);
      gload_lds16(kgl + (size_t)(kv0+row)*NQKV + (srcb >> 1), (char*)Ks + ch*1024);
    }
    // ---- stage V (4 chunks/wave) into subtiled [dblk][kv4][4][16] ----
    #pragma unroll
    for (int j=0;j<4;++j){
      int c2 = wave*4 + j;
      int dblk = c2 >> 2, kvh = c2 & 3;
      int kv = kvh*32 + v_kv;
      int d  = dblk*16 + v_d;
      gload_lds16(vgl + (size_t)(kv0+kv)*NQKV + d, (char*)Vs + c2*1024);
    }
    __syncthreads();

    // ---- QK^T swapped: S^T[kv][q]; lane(cg,cl): kv = nt*16+cg*4+i, q = cl ----
    f32x4 s[8];
    __builtin_amdgcn_s_setprio(1);
    #pragma unroll
    for (int nt=0;nt<8;++nt){
      f32x4 a = zero;
      int rowb = (nt*16 + cl)*256;
      #pragma unroll
      for (int kkq=0;kkq<4;++kkq){
        short8 kf = *(const short8*)((const char*)Ks + rowb + ((kkq*64 + cg*16) ^ keyk));
        a = __builtin_amdgcn_mfma_f32_16x16x32_bf16(kf, qf[kkq], a, 0,0,0);
      }
      s[nt] = a;
    }
    __builtin_amdgcn_s_setprio(0);

    // ---- in-register online softmax in exp2 domain (per lane: q=cl, 32 kv) ----
    float mx = s[0][0];
    #pragma unroll
    for (int nt=0;nt<8;++nt)
      #pragma unroll
      for (int i=0;i<4;++i) mx = fmaxf(mx, s[nt][i]);
    mx = fmaxf(mx, __shfl_xor(mx, 16));
    mx = fmaxf(mx, __shfl_xor(mx, 32));
    float mx2 = mx * K2;
    bool rescale = !__all(mx2 <= mrow + 11.5416f);   // defer-max, THR=8 nats
    float fac = 1.f;
    if (rescale){
      float mn = fmaxf(mrow, mx2);
      fac = exp2f(mrow - mn);
      mrow = mn;
    }
    float sum = 0.f;
    #pragma unroll
    for (int nt=0;nt<8;++nt)
      #pragma unroll
      for (int i=0;i<4;++i){
        float e = exp2f(fmaf(s[nt][i], K2, -mrow));
        s[nt][i] = e;
        sum += e;
      }
    sum += __shfl_xor(sum, 16);
    sum += __shfl_xor(sum, 32);
    lrow = lrow*fac + sum;
    if (rescale){
      float fq0 = __shfl(fac, (lane & 48) | (cg*4+0));
      float fq1 = __shfl(fac, (lane & 48) | (cg*4+1));
      float fq2 = __shfl(fac, (lane & 48) | (cg*4+2));
      float fq3 = __shfl(fac, (lane & 48) | (cg*4+3));
      #pragma unroll
      for (int dt=0;dt<8;++dt){
        f32x4 t = accO[dt];
        t[0]*=fq0; t[1]*=fq1; t[2]*=fq2; t[3]*=fq3;
        accO[dt] = t;
      }
    }

    // ---- PV in two kv-halves of 64; P bridged through per-wave LDS ----
    #pragma unroll
    for (int h2=0;h2<2;++h2){
      #pragma unroll
      for (int t=0;t<4;++t){
        int nt = h2*4 + t;
        short4v pk;
        pk[0]=(short)f2bf(s[nt][0]); pk[1]=(short)f2bf(s[nt][1]);
        pk[2]=(short)f2bf(s[nt][2]); pk[3]=(short)f2bf(s[nt][3]);
        *(short4v*)&pw[cl*64 + ((t*16 + cg*4) ^ keyc)] = pk;   // kvloc = t*16+cg*4+i
      }
      short8 pa0 = *(const short8*)&pw[cl*64 + ((cg*8)      ^ keyc)];  // kvloc = cg*8+e
      short8 pa1 = *(const short8*)&pw[cl*64 + ((32 + cg*8) ^ keyc)];  // kvloc = 32+cg*8+e

      __builtin_amdgcn_s_setprio(1);
      #pragma unroll
      for (int dt=0;dt<8;++dt){
        unsigned a0 = vbase + dt*4096 + h2*2048;
        short4v t00,t01,t10,t11;
        asm volatile("ds_read_b64_tr_b16 %0, %1"             : "=v"(t00) : "v"(a0) : "memory");
        asm volatile("ds_read_b64_tr_b16 %0, %1 offset:128"  : "=v"(t01) : "v"(a0) : "memory");
        asm volatile("ds_read_b64_tr_b16 %0, %1 offset:1024" : "=v"(t10) : "v"(a0) : "memory");
        asm volatile("ds_read_b64_tr_b16 %0, %1 offset:1152" : "=v"(t11) : "v"(a0) : "memory");
        asm volatile("s_waitcnt lgkmcnt(0)" ::: "memory");
        __builtin_amdgcn_sched_barrier(0);
        V8u b0, b1;
        b0.s.lo = t00; b0.s.hi = t01;   // window 2*h2  : kv = h2*64 + cg*8 + e
        b1.s.lo = t10; b1.s.hi = t11;   // window 2*h2+1: kv = h2*64 + 32 + cg*8 + e
        accO[dt] = __builtin_amdgcn_mfma_f32_16x16x32_bf16(pa0, b0.v, accO[dt], 0,0,0);
        accO[dt] = __builtin_amdgcn_mfma_f32_16x16x32_bf16(pa1, b1.v, accO[dt], 0,0,0);
      }
      __builtin_amdgcn_s_setprio(0);
    }
  }

  // ---- epilogue ----
  float lq0 = __shfl(lrow, (lane & 48) | (cg*4+0));
  float lq1 = __shfl(lrow, (lane & 48) | (cg*4+1));
  float lq2 = __shfl(lrow, (lane & 48) | (cg*4+2));
  float lq3 = __shfl(lrow, (lane & 48) | (cg*4+3));
  float r0 = 1.f/lq0, r1 = 1.f/lq1, r2 = 1.f/lq2, r3 = 1.f/lq3;
  size_t orow = (size_t)(b*LSEQ + q0 + wave*16 + cg*4);
  #pragma unroll
  for (int dt=0;dt<8;++dt){
    int col = h*HDIM + dt*16 + cl;
    o[(orow+0)*DMODEL + col] = f2bf(accO[dt][0]*r0);
    o[(orow+1)*DMODEL + col] = f2bf(accO[dt][1]*r1);
    o[(orow+2)*DMODEL + col] = f2bf(accO[dt][2]*r2);
    o[(orow+3)*DMODEL + col] = f2bf(accO[dt][3]*r3);
  }
}

extern "C" void kernel_launch(void* const* d_in, const int* in_sizes, int n_in,
                              void* d_out, int out_size, void* d_ws, size_t ws_size,
                              hipStream_t stream) {
  const float* x    = (const float*)d_in[0];
  const float* fcos = (const float*)d_in[1];
  const float* fsin = (const float*)d_in[2];
  const float* wqkv = (const float*)d_in[3];
  const float* bqkv = (const float*)d_in[4];
  const float* gq   = (const float*)d_in[5];
  const float* gk   = (const float*)d_in[6];
  const float* wout = (const float*)d_in[7];
  const float* bout = (const float*)d_in[8];
  float* out = (float*)d_out;

  char* ws = (char*)d_ws;
  unsigned short* xb    = (unsigned short*)(ws);                       // 16MB: x bf16
  unsigned short* qkv   = (unsigned short*)(ws + (16ull<<20));         // 48MB: qkv bf16
  unsigned short* ob    = (unsigned short*)(ws + (64ull<<20));         // 16MB: o bf16
  unsigned short* wqkvT = (unsigned short*)(ws + (80ull<<20));         // 6MB
  unsigned short* woutT = (unsigned short*)(ws + (86ull<<20));         // 2MB

  k_cvt<<<4096, 256, 0, stream>>>(x, xb, (MTOT*DMODEL)/8);
  k_transpose_cvt<<<dim3(96,32), 256, 0, stream>>>(wqkv, wqkvT, DMODEL, NQKV);
  k_transpose_cvt<<<dim3(32,32), 256, 0, stream>>>(wout, woutT, DMODEL, DMODEL);
  k_gemm_bt<1><<<dim3(NQKV/128, MTOT/128), 256, 0, stream>>>(xb, wqkvT, bqkv, qkv, MTOT, NQKV, DMODEL);
  k_norm_rope<<<MTOT, 256, 0, stream>>>(qkv, fcos, fsin, gq, gk);
  k_attn<<<dim3(LSEQ/128, 16), 512, 0, stream>>>(qkv, ob);
  k_gemm_bt<0><<<dim3(DMODEL/128, MTOT/128), 256, 0, stream>>>(ob, woutT, bout, out, MTOT, DMODEL, DMODEL);
}

// Round 5
// 338.418 us; speedup vs baseline: 1.0489x; 1.0489x over previous
//
#include <hip/hip_runtime.h>
#include <hip/hip_bf16.h>
#include <stdint.h>

typedef __attribute__((ext_vector_type(8))) short short8;
typedef __attribute__((ext_vector_type(4))) short short4v;
typedef __attribute__((ext_vector_type(4))) float f32x4;

#define LSEQ 4096
#define DMODEL 1024
#define NHEAD 8
#define HDIM 128
#define MTOT 8192
#define NQKV 3072

__device__ __forceinline__ unsigned short f2bf(float f){
  unsigned u = __float_as_uint(f);
  u += 0x7fffu + ((u >> 16) & 1u);
  return (unsigned short)(u >> 16);
}
__device__ __forceinline__ float bf2f(unsigned short h){
  return __uint_as_float(((unsigned)h) << 16);
}

typedef const __attribute__((address_space(1))) void* gas_ptr;
typedef __attribute__((address_space(3))) void* las_ptr;
__device__ __forceinline__ void gload_lds16(const void* g, void* l){
  __builtin_amdgcn_global_load_lds((gas_ptr)(uintptr_t)g,
                                   (las_ptr)(unsigned)(uintptr_t)l, 16, 0, 0);
}

// ---------------- fp32 -> bf16 cast (8 elems/thread) ----------------
__global__ __launch_bounds__(256) void k_cvt(const float* __restrict__ in,
                                             unsigned short* __restrict__ out, int n8){
  int i = blockIdx.x*256 + threadIdx.x;
  if (i >= n8) return;
  const float4* p = (const float4*)in + (size_t)i*2;
  float4 a = p[0], b = p[1];
  short8 r;
  r[0]=(short)f2bf(a.x); r[1]=(short)f2bf(a.y); r[2]=(short)f2bf(a.z); r[3]=(short)f2bf(a.w);
  r[4]=(short)f2bf(b.x); r[5]=(short)f2bf(b.y); r[6]=(short)f2bf(b.z); r[7]=(short)f2bf(b.w);
  *(short8*)(out + (size_t)i*8) = r;
}

// ---------------- fp32 [R][C] -> bf16 transposed [C][R] ----------------
__global__ __launch_bounds__(256) void k_transpose_cvt(const float* __restrict__ in,
                                                       unsigned short* __restrict__ out,
                                                       int R, int C){
  __shared__ unsigned short tile[32][33];
  int c0 = blockIdx.x*32, r0 = blockIdx.y*32;
  int tx = threadIdx.x & 31, ty = threadIdx.x >> 5;   // 32 x 8
  #pragma unroll
  for (int i=0;i<32;i+=8)
    tile[ty+i][tx] = f2bf(in[(size_t)(r0+ty+i)*C + c0+tx]);
  __syncthreads();
  #pragma unroll
  for (int i=0;i<32;i+=8)
    out[(size_t)(c0+ty+i)*R + r0+tx] = tile[tx][ty+i];
}

// ---------------- bf16 GEMM: C[M][N] = A[M][K] * Bt[N][K]^T + bias ----------------
template<int OUT_BF16>
__global__ __launch_bounds__(256) void k_gemm_bt(const unsigned short* __restrict__ A,
                                                 const unsigned short* __restrict__ Bt,
                                                 const float* __restrict__ bias,
                                                 void* __restrict__ Cout,
                                                 int M, int N, int K){
  __shared__ unsigned short As[128*64];
  __shared__ unsigned short Bs[128*64];
  int tid = threadIdx.x, lane = tid & 63, wave = tid >> 6;
  int wm = wave >> 1, wn = wave & 1;
  int m0 = blockIdx.y*128, n0 = blockIdx.x*128;
  f32x4 zero = {0.f,0.f,0.f,0.f};
  f32x4 acc[4][4];
  #pragma unroll
  for (int mi=0;mi<4;++mi)
    #pragma unroll
    for (int ni=0;ni<4;++ni) acc[mi][ni] = zero;

  int srow = lane >> 3;
  int soffb = (lane & 7) * 16;
  int scol = (soffb ^ (srow << 4)) >> 1;
  int cg = lane >> 4, cl = lane & 15;

  int nkt = K >> 6;
  for (int kt = 0; kt < nkt; ++kt){
    if (kt) __syncthreads();
    int kbase = kt*64;
    #pragma unroll
    for (int j=0;j<4;++j){
      int ch = wave*4 + j;
      int row = ch*8 + srow;
      gload_lds16(A  + (size_t)(m0+row)*K + kbase + scol, (char*)As + ch*1024);
      gload_lds16(Bt + (size_t)(n0+row)*K + kbase + scol, (char*)Bs + ch*1024);
    }
    __syncthreads();

    short8 af[4][2], bf[4][2];
    #pragma unroll
    for (int mi=0;mi<4;++mi){
      int row = wm*64 + mi*16 + cl;
      int key = (row & 7) << 4;
      #pragma unroll
      for (int kk=0;kk<2;++kk)
        af[mi][kk] = *(const short8*)((const char*)As + row*128 + ((kk*64 + cg*16) ^ key));
    }
    #pragma unroll
    for (int ni=0;ni<4;++ni){
      int row = wn*64 + ni*16 + cl;
      int key = (row & 7) << 4;
      #pragma unroll
      for (int kk=0;kk<2;++kk)
        bf[ni][kk] = *(const short8*)((const char*)Bs + row*128 + ((kk*64 + cg*16) ^ key));
    }
    #pragma unroll
    for (int kk=0;kk<2;++kk)
      #pragma unroll
      for (int mi=0;mi<4;++mi)
        #pragma unroll
        for (int ni=0;ni<4;++ni)
          acc[mi][ni] = __builtin_amdgcn_mfma_f32_16x16x32_bf16(af[mi][kk], bf[ni][kk], acc[mi][ni], 0,0,0);
  }

  #pragma unroll
  for (int ni=0;ni<4;++ni){
    int col = n0 + wn*64 + ni*16 + cl;
    float bv = bias[col];
    #pragma unroll
    for (int mi=0;mi<4;++mi){
      int r = m0 + wm*64 + mi*16 + cg*4;
      #pragma unroll
      for (int i=0;i<4;++i){
        float v = acc[mi][ni][i] + bv;
        if (OUT_BF16) ((unsigned short*)Cout)[(size_t)(r+i)*N + col] = f2bf(v);
        else          ((float*)Cout)[(size_t)(r+i)*N + col] = v;
      }
    }
  }
}

// ---------------- fused RMSNorm(q,k) + interleaved RoPE ----------------
__global__ __launch_bounds__(256) void k_norm_rope(unsigned short* __restrict__ qkv,
                                                   const float* __restrict__ fcos,
                                                   const float* __restrict__ fsin,
                                                   const float* __restrict__ gq,
                                                   const float* __restrict__ gk){
  int bl = blockIdx.x;
  int l = bl & (LSEQ-1);
  int t = threadIdx.x;
  unsigned short* row = qkv + (size_t)bl * NQKV;
  int d0 = t*4;
  short4v qv = *(short4v*)(row + d0);
  short4v kv = *(short4v*)(row + DMODEL + d0);
  float q[4], k[4];
  #pragma unroll
  for (int j=0;j<4;++j){ q[j] = bf2f((unsigned short)qv[j]); k[j] = bf2f((unsigned short)kv[j]); }
  float sq = q[0]*q[0]+q[1]*q[1]+q[2]*q[2]+q[3]*q[3];
  float sk = k[0]*k[0]+k[1]*k[1]+k[2]*k[2]+k[3]*k[3];
  #pragma unroll
  for (int o=32;o;o>>=1){ sq += __shfl_xor(sq,o); sk += __shfl_xor(sk,o); }
  __shared__ float red[8];
  int lane = t & 63, wv = t >> 6;
  if (!lane){ red[wv] = sq; red[4+wv] = sk; }
  __syncthreads();
  sq = red[0]+red[1]+red[2]+red[3];
  sk = red[4]+red[5]+red[6]+red[7];
  float rq = rsqrtf(sq*(1.f/1024.f) + 1e-6f);
  float rk = rsqrtf(sk*(1.f/1024.f) + 1e-6f);
  int hd = d0 & (HDIM-1);
  int fi = (l << 6) + (hd >> 1);
  float c0 = fcos[fi], s0 = fsin[fi], c1 = fcos[fi+1], s1 = fsin[fi+1];
  {
    float x1 = q[0]*rq*gq[d0],   x2 = q[1]*rq*gq[d0+1];
    float x3 = q[2]*rq*gq[d0+2], x4 = q[3]*rq*gq[d0+3];
    short4v qo;
    qo[0]=(short)f2bf(x1*c0 - x2*s0); qo[1]=(short)f2bf(x1*s0 + x2*c0);
    qo[2]=(short)f2bf(x3*c1 - x4*s1); qo[3]=(short)f2bf(x3*s1 + x4*c1);
    *(short4v*)(row + d0) = qo;
  }
  {
    float x1 = k[0]*rk*gk[d0],   x2 = k[1]*rk*gk[d0+1];
    float x3 = k[2]*rk*gk[d0+2], x4 = k[3]*rk*gk[d0+3];
    short4v ko;
    ko[0]=(short)f2bf(x1*c0 - x2*s0); ko[1]=(short)f2bf(x1*s0 + x2*c0);
    ko[2]=(short)f2bf(x3*c1 - x4*s1); ko[3]=(short)f2bf(x3*s1 + x4*c1);
    *(short4v*)(row + DMODEL + d0) = ko;
  }
}

// ---------------- flash attention v5: R3 structure + K double-buffer with
// counted-drain barrier, defer-max, cvt_pk P-pack, setprio ----------------
__global__ __launch_bounds__(512, 4) void k_attn(const unsigned short* __restrict__ qkv,
                                                 unsigned short* __restrict__ o){
  __shared__ unsigned short Ks[2][64*128];   // 32KB, rows 256B, XOR-swizzled content
  __shared__ unsigned short VT[128*64];      // 16KB, VT[d][kv], 8-elem-gran XOR swizzle
  __shared__ unsigned short Ps[8][16*64];    // 16KB, per-wave P bridge
  int bh = blockIdx.y; int b = bh >> 3, h = bh & 7;
  int q0 = blockIdx.x * 128;
  int tid = threadIdx.x, lane = tid & 63, wave = tid >> 6;
  int cg = lane >> 4, cl = lane & 15;
  const unsigned short* base = qkv + (size_t)b*LSEQ*NQKV + h*HDIM;
  const unsigned short* kgl = base + DMODEL;
  const unsigned short* vgl = base + 2*DMODEL;

  // Q fragments (B-operand of swapped QK^T): Q[q=cl][d=kkq*32+cg*8+e]
  short8 qf[4];
  {
    const unsigned short* qr = base + (size_t)(q0 + wave*16 + cl)*NQKV;
    #pragma unroll
    for (int kk=0;kk<4;++kk) qf[kk] = *(const short8*)(qr + kk*32 + cg*8);
  }

  const float K2 = 0.12753568849800323f;    // (1/sqrt(128)) * log2(e)
  float mrow = -3.0e38f, lrow = 0.f;
  f32x4 zero = {0.f,0.f,0.f,0.f};
  f32x4 accO[8];
  #pragma unroll
  for (int dt=0;dt<8;++dt) accO[dt] = zero;

  // V reg staging: lane = kv row, wave owns d-cols [wave*16, wave*16+16)
  const unsigned short* vsrc = vgl + (size_t)lane*NQKV + wave*16;
  short8 vr0 = *(const short8*)(vsrc);
  short8 vr1 = *(const short8*)(vsrc + 8);

  unsigned short* pw = &Ps[wave][0];
  int keyc = (cl & 7) << 3;    // element-granular XOR key (P bridge + VT reads)

  // K stage source offsets (R1-proven swizzle)
  int ksrow = cg;                         // row within 4-row chunk
  int kscol = ((cl*16) ^ 0) >> 1;         // recomputed per row below

  // ---- prologue: stage K(0) into Ks[0] ----
  #pragma unroll
  for (int j=0;j<2;++j){
    int ch = wave*2 + j;
    int row = ch*4 + cg;
    int srcb = (cl*16) ^ ((row & 7) << 4);
    gload_lds16(kgl + (size_t)row*NQKV + (srcb >> 1), (char*)Ks[0] + ch*1024);
  }
  (void)ksrow; (void)kscol;

  const int NT = LSEQ/64;
  for (int t = 0; t < NT; ++t){
    int cur = t & 1;
    __syncthreads();     // drains K(t) gloads (+V regs); all waves done with VT(t-1)

    // ---- write V regs -> VT[d][kv ^ ((d&7)<<3)] (tile t) ----
    #pragma unroll
    for (int j=0;j<8;++j){
      int xk = lane ^ (j << 3);
      VT[(wave*16 + j)*64     + xk] = (unsigned short)vr0[j];
      VT[(wave*16 + 8 + j)*64 + xk] = (unsigned short)vr1[j];
    }
    // ---- issue K(t+1) stage into alt buffer (stays in flight across barrier) ----
    if (t+1 < NT){
      int kvn = (t+1)*64;
      #pragma unroll
      for (int j=0;j<2;++j){
        int ch = wave*2 + j;
        int row = ch*4 + cg;
        int srcb = (cl*16) ^ ((row & 7) << 4);
        gload_lds16(kgl + (size_t)(kvn+row)*NQKV + (srcb >> 1), (char*)Ks[cur^1] + ch*1024);
      }
    }
    // ---- publish VT: wait LDS writes only, do NOT drain vmcnt ----
    asm volatile("s_waitcnt lgkmcnt(0)" ::: "memory");
    __builtin_amdgcn_s_barrier();

    // ---- prefetch next tile's V into regs (in flight during compute) ----
    if (t+1 < NT){
      const unsigned short* vs2 = vsrc + (size_t)(t+1)*64*NQKV;
      vr0 = *(const short8*)(vs2);
      vr1 = *(const short8*)(vs2 + 8);
    }

    // ---- QK^T swapped: S^T[kv][q]; lane(cg,cl): kv = nt*16+cg*4+i, q = cl ----
    f32x4 s[4];
    __builtin_amdgcn_s_setprio(1);
    #pragma unroll
    for (int nt=0;nt<4;++nt){
      f32x4 a = zero;
      int rowb = (nt*16 + cl)*256;
      int key = (cl & 7) << 4;
      #pragma unroll
      for (int kkq=0;kkq<4;++kkq){
        short8 kf = *(const short8*)((const char*)Ks[cur] + rowb + ((kkq*64 + cg*16) ^ key));
        a = __builtin_amdgcn_mfma_f32_16x16x32_bf16(kf, qf[kkq], a, 0,0,0);
      }
      s[nt] = a;
    }
    __builtin_amdgcn_s_setprio(0);

    // ---- in-register online softmax, exp2 domain, defer-max ----
    float mx = s[0][0];
    #pragma unroll
    for (int nt=0;nt<4;++nt)
      #pragma unroll
      for (int i=0;i<4;++i) mx = fmaxf(mx, s[nt][i]);
    mx = fmaxf(mx, __shfl_xor(mx, 16));
    mx = fmaxf(mx, __shfl_xor(mx, 32));
    float mx2 = mx * K2;
    bool rescale = !__all(mx2 <= mrow + 11.5416f);   // THR = 8 nats
    float fac = 1.f;
    if (rescale){
      float mn = fmaxf(mrow, mx2);
      fac = exp2f(mrow - mn);
      mrow = mn;
    }
    float sum = 0.f;
    #pragma unroll
    for (int nt=0;nt<4;++nt)
      #pragma unroll
      for (int i=0;i<4;++i){
        float e = exp2f(fmaf(s[nt][i], K2, -mrow));
        s[nt][i] = e;
        sum += e;
      }
    sum += __shfl_xor(sum, 16);
    sum += __shfl_xor(sum, 32);
    lrow = lrow*fac + sum;
    if (rescale){
      float fq0 = __shfl(fac, (lane & 48) | (cg*4+0));
      float fq1 = __shfl(fac, (lane & 48) | (cg*4+1));
      float fq2 = __shfl(fac, (lane & 48) | (cg*4+2));
      float fq3 = __shfl(fac, (lane & 48) | (cg*4+3));
      #pragma unroll
      for (int dt=0;dt<8;++dt){
        f32x4 tv = accO[dt];
        tv[0]*=fq0; tv[1]*=fq1; tv[2]*=fq2; tv[3]*=fq3;
        accO[dt] = tv;
      }
    }

    // ---- P pack via v_cvt_pk_bf16_f32, bridge through per-wave LDS ----
    #pragma unroll
    for (int nt=0;nt<4;++nt){
      unsigned p01, p23;
      asm("v_cvt_pk_bf16_f32 %0, %1, %2" : "=v"(p01) : "v"(s[nt][0]), "v"(s[nt][1]));
      asm("v_cvt_pk_bf16_f32 %0, %1, %2" : "=v"(p23) : "v"(s[nt][2]), "v"(s[nt][3]));
      uint2 pk; pk.x = p01; pk.y = p23;
      *(uint2*)&pw[cl*64 + ((nt*16 + cg*4) ^ keyc)] = pk;   // kv = nt*16+cg*4+{0..3}
    }
    short8 pa0 = *(const short8*)&pw[cl*64 + ((cg*8)      ^ keyc)];  // kv = cg*8+e
    short8 pa1 = *(const short8*)&pw[cl*64 + ((32 + cg*8) ^ keyc)];  // kv = 32+cg*8+e

    // ---- PV: O[q][d] += P[q][kv] V[kv][d] ----
    __builtin_amdgcn_s_setprio(1);
    #pragma unroll
    for (int dt=0;dt<8;++dt){
      const unsigned short* vrow = &VT[(dt*16 + cl)*64];
      short8 vf0 = *(const short8*)&vrow[(cg*8)      ^ keyc];
      short8 vf1 = *(const short8*)&vrow[(32 + cg*8) ^ keyc];
      accO[dt] = __builtin_amdgcn_mfma_f32_16x16x32_bf16(pa0, vf0, accO[dt], 0,0,0);
      accO[dt] = __builtin_amdgcn_mfma_f32_16x16x32_bf16(pa1, vf1, accO[dt], 0,0,0);
    }
    __builtin_amdgcn_s_setprio(0);
  }

  // ---- epilogue ----
  float lq0 = __shfl(lrow, (lane & 48) | (cg*4+0));
  float lq1 = __shfl(lrow, (lane & 48) | (cg*4+1));
  float lq2 = __shfl(lrow, (lane & 48) | (cg*4+2));
  float lq3 = __shfl(lrow, (lane & 48) | (cg*4+3));
  float r0 = 1.f/lq0, r1 = 1.f/lq1, r2 = 1.f/lq2, r3 = 1.f/lq3;
  size_t orow = (size_t)(b*LSEQ + q0 + wave*16 + cg*4);
  #pragma unroll
  for (int dt=0;dt<8;++dt){
    int col = h*HDIM + dt*16 + cl;
    o[(orow+0)*DMODEL + col] = f2bf(accO[dt][0]*r0);
    o[(orow+1)*DMODEL + col] = f2bf(accO[dt][1]*r1);
    o[(orow+2)*DMODEL + col] = f2bf(accO[dt][2]*r2);
    o[(orow+3)*DMODEL + col] = f2bf(accO[dt][3]*r3);
  }
}

extern "C" void kernel_launch(void* const* d_in, const int* in_sizes, int n_in,
                              void* d_out, int out_size, void* d_ws, size_t ws_size,
                              hipStream_t stream) {
  const float* x    = (const float*)d_in[0];
  const float* fcos = (const float*)d_in[1];
  const float* fsin = (const float*)d_in[2];
  const float* wqkv = (const float*)d_in[3];
  const float* bqkv = (const float*)d_in[4];
  const float* gq   = (const float*)d_in[5];
  const float* gk   = (const float*)d_in[6];
  const float* wout = (const float*)d_in[7];
  const float* bout = (const float*)d_in[8];
  float* out = (float*)d_out;

  char* ws = (char*)d_ws;
  unsigned short* xb    = (unsigned short*)(ws);                       // 16MB: x bf16
  unsigned short* qkv   = (unsigned short*)(ws + (16ull<<20));         // 48MB: qkv bf16
  unsigned short* ob    = (unsigned short*)(ws + (64ull<<20));         // 16MB: o bf16
  unsigned short* wqkvT = (unsigned short*)(ws + (80ull<<20));         // 6MB
  unsigned short* woutT = (unsigned short*)(ws + (86ull<<20));         // 2MB

  k_cvt<<<4096, 256, 0, stream>>>(x, xb, (MTOT*DMODEL)/8);
  k_transpose_cvt<<<dim3(96,32), 256, 0, stream>>>(wqkv, wqkvT, DMODEL, NQKV);
  k_transpose_cvt<<<dim3(32,32), 256, 0, stream>>>(wout, woutT, DMODEL, DMODEL);
  k_gemm_bt<1><<<dim3(NQKV/128, MTOT/128), 256, 0, stream>>>(xb, wqkvT, bqkv, qkv, MTOT, NQKV, DMODEL);
  k_norm_rope<<<MTOT, 256, 0, stream>>>(qkv, fcos, fsin, gq, gk);
  k_attn<<<dim3(LSEQ/128, 16), 512, 0, stream>>>(qkv, ob);
  k_gemm_bt<0><<<dim3(DMODEL/128, MTOT/128), 256, 0, stream>>>(ob, woutT, bout, out, MTOT, DMODEL, DMODEL);
}

// Round 6
// 333.391 us; speedup vs baseline: 1.0647x; 1.0151x over previous
//
#include <hip/hip_runtime.h>
#include <hip/hip_bf16.h>
#include <stdint.h>

typedef __attribute__((ext_vector_type(8))) short short8;
typedef __attribute__((ext_vector_type(4))) short short4v;
typedef __attribute__((ext_vector_type(4))) float f32x4;

#define LSEQ 4096
#define DMODEL 1024
#define NHEAD 8
#define HDIM 128
#define MTOT 8192
#define NQKV 3072

__device__ __forceinline__ unsigned short f2bf(float f){
  unsigned u = __float_as_uint(f);
  u += 0x7fffu + ((u >> 16) & 1u);
  return (unsigned short)(u >> 16);
}
__device__ __forceinline__ float bf2f(unsigned short h){
  return __uint_as_float(((unsigned)h) << 16);
}

typedef const __attribute__((address_space(1))) void* gas_ptr;
typedef __attribute__((address_space(3))) void* las_ptr;
__device__ __forceinline__ void gload_lds16(const void* g, void* l){
  __builtin_amdgcn_global_load_lds((gas_ptr)(uintptr_t)g,
                                   (las_ptr)(unsigned)(uintptr_t)l, 16, 0, 0);
}

// ---------------- fp32 -> bf16 cast (8 elems/thread) ----------------
__global__ __launch_bounds__(256) void k_cvt(const float* __restrict__ in,
                                             unsigned short* __restrict__ out, int n8){
  int i = blockIdx.x*256 + threadIdx.x;
  if (i >= n8) return;
  const float4* p = (const float4*)in + (size_t)i*2;
  float4 a = p[0], b = p[1];
  short8 r;
  r[0]=(short)f2bf(a.x); r[1]=(short)f2bf(a.y); r[2]=(short)f2bf(a.z); r[3]=(short)f2bf(a.w);
  r[4]=(short)f2bf(b.x); r[5]=(short)f2bf(b.y); r[6]=(short)f2bf(b.z); r[7]=(short)f2bf(b.w);
  *(short8*)(out + (size_t)i*8) = r;
}

// ---------------- fp32 [R][C] -> bf16 transposed [C][R] ----------------
__global__ __launch_bounds__(256) void k_transpose_cvt(const float* __restrict__ in,
                                                       unsigned short* __restrict__ out,
                                                       int R, int C){
  __shared__ unsigned short tile[32][33];
  int c0 = blockIdx.x*32, r0 = blockIdx.y*32;
  int tx = threadIdx.x & 31, ty = threadIdx.x >> 5;   // 32 x 8
  #pragma unroll
  for (int i=0;i<32;i+=8)
    tile[ty+i][tx] = f2bf(in[(size_t)(r0+ty+i)*C + c0+tx]);
  __syncthreads();
  #pragma unroll
  for (int i=0;i<32;i+=8)
    out[(size_t)(c0+ty+i)*R + r0+tx] = tile[tx][ty+i];
}

// ---------------- bf16 GEMM: C[M][N] = A[M][K] * Bt[N][K]^T + bias ----------------
template<int OUT_BF16>
__global__ __launch_bounds__(256) void k_gemm_bt(const unsigned short* __restrict__ A,
                                                 const unsigned short* __restrict__ Bt,
                                                 const float* __restrict__ bias,
                                                 void* __restrict__ Cout,
                                                 int M, int N, int K){
  __shared__ unsigned short As[128*64];
  __shared__ unsigned short Bs[128*64];
  int tid = threadIdx.x, lane = tid & 63, wave = tid >> 6;
  int wm = wave >> 1, wn = wave & 1;
  int m0 = blockIdx.y*128, n0 = blockIdx.x*128;
  f32x4 zero = {0.f,0.f,0.f,0.f};
  f32x4 acc[4][4];
  #pragma unroll
  for (int mi=0;mi<4;++mi)
    #pragma unroll
    for (int ni=0;ni<4;++ni) acc[mi][ni] = zero;

  int srow = lane >> 3;
  int soffb = (lane & 7) * 16;
  int scol = (soffb ^ (srow << 4)) >> 1;
  int cg = lane >> 4, cl = lane & 15;

  int nkt = K >> 6;
  for (int kt = 0; kt < nkt; ++kt){
    if (kt) __syncthreads();
    int kbase = kt*64;
    #pragma unroll
    for (int j=0;j<4;++j){
      int ch = wave*4 + j;
      int row = ch*8 + srow;
      gload_lds16(A  + (size_t)(m0+row)*K + kbase + scol, (char*)As + ch*1024);
      gload_lds16(Bt + (size_t)(n0+row)*K + kbase + scol, (char*)Bs + ch*1024);
    }
    __syncthreads();

    short8 af[4][2], bf[4][2];
    #pragma unroll
    for (int mi=0;mi<4;++mi){
      int row = wm*64 + mi*16 + cl;
      int key = (row & 7) << 4;
      #pragma unroll
      for (int kk=0;kk<2;++kk)
        af[mi][kk] = *(const short8*)((const char*)As + row*128 + ((kk*64 + cg*16) ^ key));
    }
    #pragma unroll
    for (int ni=0;ni<4;++ni){
      int row = wn*64 + ni*16 + cl;
      int key = (row & 7) << 4;
      #pragma unroll
      for (int kk=0;kk<2;++kk)
        bf[ni][kk] = *(const short8*)((const char*)Bs + row*128 + ((kk*64 + cg*16) ^ key));
    }
    #pragma unroll
    for (int kk=0;kk<2;++kk)
      #pragma unroll
      for (int mi=0;mi<4;++mi)
        #pragma unroll
        for (int ni=0;ni<4;++ni)
          acc[mi][ni] = __builtin_amdgcn_mfma_f32_16x16x32_bf16(af[mi][kk], bf[ni][kk], acc[mi][ni], 0,0,0);
  }

  #pragma unroll
  for (int ni=0;ni<4;++ni){
    int col = n0 + wn*64 + ni*16 + cl;
    float bv = bias[col];
    #pragma unroll
    for (int mi=0;mi<4;++mi){
      int r = m0 + wm*64 + mi*16 + cg*4;
      #pragma unroll
      for (int i=0;i<4;++i){
        float v = acc[mi][ni][i] + bv;
        if (OUT_BF16) ((unsigned short*)Cout)[(size_t)(r+i)*N + col] = f2bf(v);
        else          ((float*)Cout)[(size_t)(r+i)*N + col] = v;
      }
    }
  }
}

// ---------------- fused RMSNorm(q,k) + interleaved RoPE ----------------
__global__ __launch_bounds__(256) void k_norm_rope(unsigned short* __restrict__ qkv,
                                                   const float* __restrict__ fcos,
                                                   const float* __restrict__ fsin,
                                                   const float* __restrict__ gq,
                                                   const float* __restrict__ gk){
  int bl = blockIdx.x;
  int l = bl & (LSEQ-1);
  int t = threadIdx.x;
  unsigned short* row = qkv + (size_t)bl * NQKV;
  int d0 = t*4;
  short4v qv = *(short4v*)(row + d0);
  short4v kv = *(short4v*)(row + DMODEL + d0);
  float q[4], k[4];
  #pragma unroll
  for (int j=0;j<4;++j){ q[j] = bf2f((unsigned short)qv[j]); k[j] = bf2f((unsigned short)kv[j]); }
  float sq = q[0]*q[0]+q[1]*q[1]+q[2]*q[2]+q[3]*q[3];
  float sk = k[0]*k[0]+k[1]*k[1]+k[2]*k[2]+k[3]*k[3];
  #pragma unroll
  for (int o=32;o;o>>=1){ sq += __shfl_xor(sq,o); sk += __shfl_xor(sk,o); }
  __shared__ float red[8];
  int lane = t & 63, wv = t >> 6;
  if (!lane){ red[wv] = sq; red[4+wv] = sk; }
  __syncthreads();
  sq = red[0]+red[1]+red[2]+red[3];
  sk = red[4]+red[5]+red[6]+red[7];
  float rq = rsqrtf(sq*(1.f/1024.f) + 1e-6f);
  float rk = rsqrtf(sk*(1.f/1024.f) + 1e-6f);
  int hd = d0 & (HDIM-1);
  int fi = (l << 6) + (hd >> 1);
  float c0 = fcos[fi], s0 = fsin[fi], c1 = fcos[fi+1], s1 = fsin[fi+1];
  {
    float x1 = q[0]*rq*gq[d0],   x2 = q[1]*rq*gq[d0+1];
    float x3 = q[2]*rq*gq[d0+2], x4 = q[3]*rq*gq[d0+3];
    short4v qo;
    qo[0]=(short)f2bf(x1*c0 - x2*s0); qo[1]=(short)f2bf(x1*s0 + x2*c0);
    qo[2]=(short)f2bf(x3*c1 - x4*s1); qo[3]=(short)f2bf(x3*s1 + x4*c1);
    *(short4v*)(row + d0) = qo;
  }
  {
    float x1 = k[0]*rk*gk[d0],   x2 = k[1]*rk*gk[d0+1];
    float x3 = k[2]*rk*gk[d0+2], x4 = k[3]*rk*gk[d0+3];
    short4v ko;
    ko[0]=(short)f2bf(x1*c0 - x2*s0); ko[1]=(short)f2bf(x1*s0 + x2*c0);
    ko[2]=(short)f2bf(x3*c1 - x4*s1); ko[3]=(short)f2bf(x3*s1 + x4*c1);
    *(short4v*)(row + DMODEL + d0) = ko;
  }
}

// ---------------- flash attention v6: 4 waves x 32 q-rows (2 q-frags/wave),
// every K/V fragment read feeds 2 MFMAs; K dbuf + counted-drain barrier,
// defer-max, exp2 softmax, cvt_pk P-pack, setprio ----------------
__global__ __launch_bounds__(256, 2) void k_attn(const unsigned short* __restrict__ qkv,
                                                 unsigned short* __restrict__ o){
  __shared__ unsigned short Ks[2][64*128];   // 32KB, rows 256B, XOR-swizzled content
  __shared__ unsigned short VT[128*64];      // 16KB, VT[d][kv], 8-elem-gran XOR swizzle
  __shared__ unsigned short Ps[4][2][16*64]; // 16KB, per-wave-per-qset P bridge
  int bh = blockIdx.y; int b = bh >> 3, h = bh & 7;
  int q0 = blockIdx.x * 128;
  int tid = threadIdx.x, lane = tid & 63, wave = tid >> 6;
  int cg = lane >> 4, cl = lane & 15;
  const unsigned short* base = qkv + (size_t)b*LSEQ*NQKV + h*HDIM;
  const unsigned short* kgl = base + DMODEL;
  const unsigned short* vgl = base + 2*DMODEL;

  // Q fragments (B-operand of swapped QK^T): two q-subtiles per wave
  short8 qf[2][4];
  #pragma unroll
  for (int qs=0;qs<2;++qs){
    const unsigned short* qr = base + (size_t)(q0 + wave*32 + qs*16 + cl)*NQKV;
    #pragma unroll
    for (int kk=0;kk<4;++kk) qf[qs][kk] = *(const short8*)(qr + kk*32 + cg*8);
  }

  const float K2 = 0.12753568849800323f;    // (1/sqrt(128)) * log2(e)
  float mrow[2] = {-3.0e38f, -3.0e38f}, lrow[2] = {0.f, 0.f};
  f32x4 zero = {0.f,0.f,0.f,0.f};
  f32x4 accO[2][8];
  #pragma unroll
  for (int qs=0;qs<2;++qs)
    #pragma unroll
    for (int dt=0;dt<8;++dt) accO[qs][dt] = zero;

  // V reg staging: lane = kv row, wave owns d-cols [wave*32, wave*32+32)
  const unsigned short* vsrc = vgl + (size_t)lane*NQKV + wave*32;
  short8 vr0 = *(const short8*)(vsrc);
  short8 vr1 = *(const short8*)(vsrc + 8);
  short8 vr2 = *(const short8*)(vsrc + 16);
  short8 vr3 = *(const short8*)(vsrc + 24);

  int keyc = (cl & 7) << 3;    // element-granular XOR key (P bridge + VT reads)

  // ---- prologue: stage K(0) into Ks[0] (16 chunks over 4 waves) ----
  #pragma unroll
  for (int j=0;j<4;++j){
    int ch = wave*4 + j;
    int row = ch*4 + cg;
    int srcb = (cl*16) ^ ((row & 7) << 4);
    gload_lds16(kgl + (size_t)row*NQKV + (srcb >> 1), (char*)Ks[0] + ch*1024);
  }

  const int NT = LSEQ/64;
  for (int t = 0; t < NT; ++t){
    int cur = t & 1;
    __syncthreads();     // drains K(t) gloads + V regs; all waves done with VT(t-1)

    // ---- write V regs -> VT[d][kv ^ ((d&7)<<3)] (tile t), 32 d-rows/wave ----
    #pragma unroll
    for (int j=0;j<8;++j){
      int xk = lane ^ (j << 3);
      VT[(wave*32 +      j)*64 + xk] = (unsigned short)vr0[j];
      VT[(wave*32 +  8 + j)*64 + xk] = (unsigned short)vr1[j];
      VT[(wave*32 + 16 + j)*64 + xk] = (unsigned short)vr2[j];
      VT[(wave*32 + 24 + j)*64 + xk] = (unsigned short)vr3[j];
    }
    // ---- issue K(t+1) stage into alt buffer (stays in flight across barrier) ----
    if (t+1 < NT){
      int kvn = (t+1)*64;
      #pragma unroll
      for (int j=0;j<4;++j){
        int ch = wave*4 + j;
        int row = ch*4 + cg;
        int srcb = (cl*16) ^ ((row & 7) << 4);
        gload_lds16(kgl + (size_t)(kvn+row)*NQKV + (srcb >> 1), (char*)Ks[cur^1] + ch*1024);
      }
    }
    // ---- publish VT: wait LDS writes only, do NOT drain vmcnt ----
    asm volatile("s_waitcnt lgkmcnt(0)" ::: "memory");
    __builtin_amdgcn_s_barrier();

    // ---- prefetch next tile's V into regs (in flight during compute) ----
    if (t+1 < NT){
      const unsigned short* vs2 = vsrc + (size_t)(t+1)*64*NQKV;
      vr0 = *(const short8*)(vs2);
      vr1 = *(const short8*)(vs2 + 8);
      vr2 = *(const short8*)(vs2 + 16);
      vr3 = *(const short8*)(vs2 + 24);
    }

    // ---- QK^T swapped: S^T[kv][q]; each kf read feeds both q-subtiles ----
    f32x4 s[2][4];
    __builtin_amdgcn_s_setprio(1);
    #pragma unroll
    for (int nt=0;nt<4;++nt){
      f32x4 a0 = zero, a1 = zero;
      int rowb = (nt*16 + cl)*256;
      int key = (cl & 7) << 4;
      #pragma unroll
      for (int kkq=0;kkq<4;++kkq){
        short8 kf = *(const short8*)((const char*)Ks[cur] + rowb + ((kkq*64 + cg*16) ^ key));
        a0 = __builtin_amdgcn_mfma_f32_16x16x32_bf16(kf, qf[0][kkq], a0, 0,0,0);
        a1 = __builtin_amdgcn_mfma_f32_16x16x32_bf16(kf, qf[1][kkq], a1, 0,0,0);
      }
      s[0][nt] = a0;
      s[1][nt] = a1;
    }
    __builtin_amdgcn_s_setprio(0);

    // ---- in-register online softmax, exp2 domain, defer-max (per q-set) ----
    #pragma unroll
    for (int qs=0;qs<2;++qs){
      float mx = s[qs][0][0];
      #pragma unroll
      for (int nt=0;nt<4;++nt)
        #pragma unroll
        for (int i=0;i<4;++i) mx = fmaxf(mx, s[qs][nt][i]);
      mx = fmaxf(mx, __shfl_xor(mx, 16));
      mx = fmaxf(mx, __shfl_xor(mx, 32));
      float mx2 = mx * K2;
      bool rescale = !__all(mx2 <= mrow[qs] + 11.5416f);   // THR = 8 nats
      float fac = 1.f;
      if (rescale){
        float mn = fmaxf(mrow[qs], mx2);
        fac = exp2f(mrow[qs] - mn);
        mrow[qs] = mn;
      }
      float sum = 0.f;
      #pragma unroll
      for (int nt=0;nt<4;++nt)
        #pragma unroll
        for (int i=0;i<4;++i){
          float e = exp2f(fmaf(s[qs][nt][i], K2, -mrow[qs]));
          s[qs][nt][i] = e;
          sum += e;
        }
      sum += __shfl_xor(sum, 16);
      sum += __shfl_xor(sum, 32);
      lrow[qs] = lrow[qs]*fac + sum;
      if (rescale){
        float fq0 = __shfl(fac, (lane & 48) | (cg*4+0));
        float fq1 = __shfl(fac, (lane & 48) | (cg*4+1));
        float fq2 = __shfl(fac, (lane & 48) | (cg*4+2));
        float fq3 = __shfl(fac, (lane & 48) | (cg*4+3));
        #pragma unroll
        for (int dt=0;dt<8;++dt){
          f32x4 tv = accO[qs][dt];
          tv[0]*=fq0; tv[1]*=fq1; tv[2]*=fq2; tv[3]*=fq3;
          accO[qs][dt] = tv;
        }
      }
    }

    // ---- P pack via v_cvt_pk_bf16_f32, bridge through per-wave LDS ----
    short8 pa0[2], pa1[2];
    #pragma unroll
    for (int qs=0;qs<2;++qs){
      unsigned short* pw = &Ps[wave][qs][0];
      #pragma unroll
      for (int nt=0;nt<4;++nt){
        unsigned p01, p23;
        asm("v_cvt_pk_bf16_f32 %0, %1, %2" : "=v"(p01) : "v"(s[qs][nt][0]), "v"(s[qs][nt][1]));
        asm("v_cvt_pk_bf16_f32 %0, %1, %2" : "=v"(p23) : "v"(s[qs][nt][2]), "v"(s[qs][nt][3]));
        uint2 pk; pk.x = p01; pk.y = p23;
        *(uint2*)&pw[cl*64 + ((nt*16 + cg*4) ^ keyc)] = pk;   // kv = nt*16+cg*4+{0..3}
      }
      pa0[qs] = *(const short8*)&pw[cl*64 + ((cg*8)      ^ keyc)];  // kv = cg*8+e
      pa1[qs] = *(const short8*)&pw[cl*64 + ((32 + cg*8) ^ keyc)];  // kv = 32+cg*8+e
    }

    // ---- PV: each vf read feeds both q-subtiles ----
    __builtin_amdgcn_s_setprio(1);
    #pragma unroll
    for (int dt=0;dt<8;++dt){
      const unsigned short* vrow = &VT[(dt*16 + cl)*64];
      short8 vf0 = *(const short8*)&vrow[(cg*8)      ^ keyc];
      short8 vf1 = *(const short8*)&vrow[(32 + cg*8) ^ keyc];
      accO[0][dt] = __builtin_amdgcn_mfma_f32_16x16x32_bf16(pa0[0], vf0, accO[0][dt], 0,0,0);
      accO[0][dt] = __builtin_amdgcn_mfma_f32_16x16x32_bf16(pa1[0], vf1, accO[0][dt], 0,0,0);
      accO[1][dt] = __builtin_amdgcn_mfma_f32_16x16x32_bf16(pa0[1], vf0, accO[1][dt], 0,0,0);
      accO[1][dt] = __builtin_amdgcn_mfma_f32_16x16x32_bf16(pa1[1], vf1, accO[1][dt], 0,0,0);
    }
    __builtin_amdgcn_s_setprio(0);
  }

  // ---- epilogue ----
  #pragma unroll
  for (int qs=0;qs<2;++qs){
    float lq0 = __shfl(lrow[qs], (lane & 48) | (cg*4+0));
    float lq1 = __shfl(lrow[qs], (lane & 48) | (cg*4+1));
    float lq2 = __shfl(lrow[qs], (lane & 48) | (cg*4+2));
    float lq3 = __shfl(lrow[qs], (lane & 48) | (cg*4+3));
    float r0 = 1.f/lq0, r1 = 1.f/lq1, r2 = 1.f/lq2, r3 = 1.f/lq3;
    size_t orow = (size_t)(b*LSEQ + q0 + wave*32 + qs*16 + cg*4);
    #pragma unroll
    for (int dt=0;dt<8;++dt){
      int col = h*HDIM + dt*16 + cl;
      o[(orow+0)*DMODEL + col] = f2bf(accO[qs][dt][0]*r0);
      o[(orow+1)*DMODEL + col] = f2bf(accO[qs][dt][1]*r1);
      o[(orow+2)*DMODEL + col] = f2bf(accO[qs][dt][2]*r2);
      o[(orow+3)*DMODEL + col] = f2bf(accO[qs][dt][3]*r3);
    }
  }
}

extern "C" void kernel_launch(void* const* d_in, const int* in_sizes, int n_in,
                              void* d_out, int out_size, void* d_ws, size_t ws_size,
                              hipStream_t stream) {
  const float* x    = (const float*)d_in[0];
  const float* fcos = (const float*)d_in[1];
  const float* fsin = (const float*)d_in[2];
  const float* wqkv = (const float*)d_in[3];
  const float* bqkv = (const float*)d_in[4];
  const float* gq   = (const float*)d_in[5];
  const float* gk   = (const float*)d_in[6];
  const float* wout = (const float*)d_in[7];
  const float* bout = (const float*)d_in[8];
  float* out = (float*)d_out;

  char* ws = (char*)d_ws;
  unsigned short* xb    = (unsigned short*)(ws);                       // 16MB: x bf16
  unsigned short* qkv   = (unsigned short*)(ws + (16ull<<20));         // 48MB: qkv bf16
  unsigned short* ob    = (unsigned short*)(ws + (64ull<<20));         // 16MB: o bf16
  unsigned short* wqkvT = (unsigned short*)(ws + (80ull<<20));         // 6MB
  unsigned short* woutT = (unsigned short*)(ws + (86ull<<20));         // 2MB

  k_cvt<<<4096, 256, 0, stream>>>(x, xb, (MTOT*DMODEL)/8);
  k_transpose_cvt<<<dim3(96,32), 256, 0, stream>>>(wqkv, wqkvT, DMODEL, NQKV);
  k_transpose_cvt<<<dim3(32,32), 256, 0, stream>>>(wout, woutT, DMODEL, DMODEL);
  k_gemm_bt<1><<<dim3(NQKV/128, MTOT/128), 256, 0, stream>>>(xb, wqkvT, bqkv, qkv, MTOT, NQKV, DMODEL);
  k_norm_rope<<<MTOT, 256, 0, stream>>>(qkv, fcos, fsin, gq, gk);
  k_attn<<<dim3(LSEQ/128, 16), 256, 0, stream>>>(qkv, ob);
  k_gemm_bt<0><<<dim3(DMODEL/128, MTOT/128), 256, 0, stream>>>(ob, woutT, bout, out, MTOT, DMODEL, DMODEL);
}

// Round 7
// 323.055 us; speedup vs baseline: 1.0988x; 1.0320x over previous
//
#include <hip/hip_runtime.h>
#include <hip/hip_bf16.h>
#include <stdint.h>

typedef __attribute__((ext_vector_type(8))) short short8;
typedef __attribute__((ext_vector_type(4))) short short4v;
typedef __attribute__((ext_vector_type(4))) float f32x4;

#define LSEQ 4096
#define DMODEL 1024
#define NHEAD 8
#define HDIM 128
#define MTOT 8192
#define NQKV 3072

__device__ __forceinline__ unsigned short f2bf(float f){
  unsigned u = __float_as_uint(f);
  u += 0x7fffu + ((u >> 16) & 1u);
  return (unsigned short)(u >> 16);
}
__device__ __forceinline__ float bf2f(unsigned short h){
  return __uint_as_float(((unsigned)h) << 16);
}

typedef const __attribute__((address_space(1))) void* gas_ptr;
typedef __attribute__((address_space(3))) void* las_ptr;
__device__ __forceinline__ void gload_lds16(const void* g, void* l){
  __builtin_amdgcn_global_load_lds((gas_ptr)(uintptr_t)g,
                                   (las_ptr)(unsigned)(uintptr_t)l, 16, 0, 0);
}

// ---------------- fp32 -> bf16 cast (8 elems/thread) ----------------
__global__ __launch_bounds__(256) void k_cvt(const float* __restrict__ in,
                                             unsigned short* __restrict__ out, int n8){
  int i = blockIdx.x*256 + threadIdx.x;
  if (i >= n8) return;
  const float4* p = (const float4*)in + (size_t)i*2;
  float4 a = p[0], b = p[1];
  short8 r;
  r[0]=(short)f2bf(a.x); r[1]=(short)f2bf(a.y); r[2]=(short)f2bf(a.z); r[3]=(short)f2bf(a.w);
  r[4]=(short)f2bf(b.x); r[5]=(short)f2bf(b.y); r[6]=(short)f2bf(b.z); r[7]=(short)f2bf(b.w);
  *(short8*)(out + (size_t)i*8) = r;
}

// ---------------- fp32 [R][C] -> bf16 transposed [C][R] ----------------
__global__ __launch_bounds__(256) void k_transpose_cvt(const float* __restrict__ in,
                                                       unsigned short* __restrict__ out,
                                                       int R, int C){
  __shared__ unsigned short tile[32][33];
  int c0 = blockIdx.x*32, r0 = blockIdx.y*32;
  int tx = threadIdx.x & 31, ty = threadIdx.x >> 5;   // 32 x 8
  #pragma unroll
  for (int i=0;i<32;i+=8)
    tile[ty+i][tx] = f2bf(in[(size_t)(r0+ty+i)*C + c0+tx]);
  __syncthreads();
  #pragma unroll
  for (int i=0;i<32;i+=8)
    out[(size_t)(c0+ty+i)*R + r0+tx] = tile[tx][ty+i];
}

// ---------------- bf16 V -> V^T per head: vT[bh][d][l] ----------------
__global__ __launch_bounds__(256) void k_vT(const unsigned short* __restrict__ qkv,
                                            unsigned short* __restrict__ vT){
  __shared__ unsigned short tile[32][33];
  int bh = blockIdx.z; int b = bh >> 3, h = bh & 7;
  int l0 = blockIdx.x*32, d0 = blockIdx.y*32;
  const unsigned short* src = qkv + (size_t)b*LSEQ*NQKV + 2*DMODEL + h*HDIM;
  int tx = threadIdx.x & 31, ty = threadIdx.x >> 5;   // 32 x 8
  #pragma unroll
  for (int i=0;i<32;i+=8)
    tile[ty+i][tx] = src[(size_t)(l0+ty+i)*NQKV + d0+tx];
  __syncthreads();
  unsigned short* dst = vT + ((size_t)bh*HDIM + d0)*LSEQ + l0;
  #pragma unroll
  for (int i=0;i<32;i+=8)
    dst[(size_t)(ty+i)*LSEQ + tx] = tile[tx][ty+i];
}

// ---------------- bf16 GEMM: C[M][N] = A[M][K] * Bt[N][K]^T + bias ----------------
template<int OUT_BF16>
__global__ __launch_bounds__(256) void k_gemm_bt(const unsigned short* __restrict__ A,
                                                 const unsigned short* __restrict__ Bt,
                                                 const float* __restrict__ bias,
                                                 void* __restrict__ Cout,
                                                 int M, int N, int K){
  __shared__ unsigned short As[128*64];
  __shared__ unsigned short Bs[128*64];
  int tid = threadIdx.x, lane = tid & 63, wave = tid >> 6;
  int wm = wave >> 1, wn = wave & 1;
  int m0 = blockIdx.y*128, n0 = blockIdx.x*128;
  f32x4 zero = {0.f,0.f,0.f,0.f};
  f32x4 acc[4][4];
  #pragma unroll
  for (int mi=0;mi<4;++mi)
    #pragma unroll
    for (int ni=0;ni<4;++ni) acc[mi][ni] = zero;

  int srow = lane >> 3;
  int soffb = (lane & 7) * 16;
  int scol = (soffb ^ (srow << 4)) >> 1;
  int cg = lane >> 4, cl = lane & 15;

  int nkt = K >> 6;
  for (int kt = 0; kt < nkt; ++kt){
    if (kt) __syncthreads();
    int kbase = kt*64;
    #pragma unroll
    for (int j=0;j<4;++j){
      int ch = wave*4 + j;
      int row = ch*8 + srow;
      gload_lds16(A  + (size_t)(m0+row)*K + kbase + scol, (char*)As + ch*1024);
      gload_lds16(Bt + (size_t)(n0+row)*K + kbase + scol, (char*)Bs + ch*1024);
    }
    __syncthreads();

    short8 af[4][2], bf[4][2];
    #pragma unroll
    for (int mi=0;mi<4;++mi){
      int row = wm*64 + mi*16 + cl;
      int key = (row & 7) << 4;
      #pragma unroll
      for (int kk=0;kk<2;++kk)
        af[mi][kk] = *(const short8*)((const char*)As + row*128 + ((kk*64 + cg*16) ^ key));
    }
    #pragma unroll
    for (int ni=0;ni<4;++ni){
      int row = wn*64 + ni*16 + cl;
      int key = (row & 7) << 4;
      #pragma unroll
      for (int kk=0;kk<2;++kk)
        bf[ni][kk] = *(const short8*)((const char*)Bs + row*128 + ((kk*64 + cg*16) ^ key));
    }
    #pragma unroll
    for (int kk=0;kk<2;++kk)
      #pragma unroll
      for (int mi=0;mi<4;++mi)
        #pragma unroll
        for (int ni=0;ni<4;++ni)
          acc[mi][ni] = __builtin_amdgcn_mfma_f32_16x16x32_bf16(af[mi][kk], bf[ni][kk], acc[mi][ni], 0,0,0);
  }

  #pragma unroll
  for (int ni=0;ni<4;++ni){
    int col = n0 + wn*64 + ni*16 + cl;
    float bv = bias[col];
    #pragma unroll
    for (int mi=0;mi<4;++mi){
      int r = m0 + wm*64 + mi*16 + cg*4;
      #pragma unroll
      for (int i=0;i<4;++i){
        float v = acc[mi][ni][i] + bv;
        if (OUT_BF16) ((unsigned short*)Cout)[(size_t)(r+i)*N + col] = f2bf(v);
        else          ((float*)Cout)[(size_t)(r+i)*N + col] = v;
      }
    }
  }
}

// ---------------- fused RMSNorm(q,k) + interleaved RoPE ----------------
__global__ __launch_bounds__(256) void k_norm_rope(unsigned short* __restrict__ qkv,
                                                   const float* __restrict__ fcos,
                                                   const float* __restrict__ fsin,
                                                   const float* __restrict__ gq,
                                                   const float* __restrict__ gk){
  int bl = blockIdx.x;
  int l = bl & (LSEQ-1);
  int t = threadIdx.x;
  unsigned short* row = qkv + (size_t)bl * NQKV;
  int d0 = t*4;
  short4v qv = *(short4v*)(row + d0);
  short4v kv = *(short4v*)(row + DMODEL + d0);
  float q[4], k[4];
  #pragma unroll
  for (int j=0;j<4;++j){ q[j] = bf2f((unsigned short)qv[j]); k[j] = bf2f((unsigned short)kv[j]); }
  float sq = q[0]*q[0]+q[1]*q[1]+q[2]*q[2]+q[3]*q[3];
  float sk = k[0]*k[0]+k[1]*k[1]+k[2]*k[2]+k[3]*k[3];
  #pragma unroll
  for (int o=32;o;o>>=1){ sq += __shfl_xor(sq,o); sk += __shfl_xor(sk,o); }
  __shared__ float red[8];
  int lane = t & 63, wv = t >> 6;
  if (!lane){ red[wv] = sq; red[4+wv] = sk; }
  __syncthreads();
  sq = red[0]+red[1]+red[2]+red[3];
  sk = red[4]+red[5]+red[6]+red[7];
  float rq = rsqrtf(sq*(1.f/1024.f) + 1e-6f);
  float rk = rsqrtf(sk*(1.f/1024.f) + 1e-6f);
  int hd = d0 & (HDIM-1);
  int fi = (l << 6) + (hd >> 1);
  float c0 = fcos[fi], s0 = fsin[fi], c1 = fcos[fi+1], s1 = fsin[fi+1];
  {
    float x1 = q[0]*rq*gq[d0],   x2 = q[1]*rq*gq[d0+1];
    float x3 = q[2]*rq*gq[d0+2], x4 = q[3]*rq*gq[d0+3];
    short4v qo;
    qo[0]=(short)f2bf(x1*c0 - x2*s0); qo[1]=(short)f2bf(x1*s0 + x2*c0);
    qo[2]=(short)f2bf(x3*c1 - x4*s1); qo[3]=(short)f2bf(x3*s1 + x4*c1);
    *(short4v*)(row + d0) = qo;
  }
  {
    float x1 = k[0]*rk*gk[d0],   x2 = k[1]*rk*gk[d0+1];
    float x3 = k[2]*rk*gk[d0+2], x4 = k[3]*rk*gk[d0+3];
    short4v ko;
    ko[0]=(short)f2bf(x1*c0 - x2*s0); ko[1]=(short)f2bf(x1*s0 + x2*c0);
    ko[2]=(short)f2bf(x3*c1 - x4*s1); ko[3]=(short)f2bf(x3*s1 + x4*c1);
    *(short4v*)(row + DMODEL + d0) = ko;
  }
}

// ---------------- flash attention v7: 4 waves x 32 q-rows, K+V^T both staged
// via swizzled global_load_lds (dbuf), 1 barrier/tile, exp2 softmax + defer-max,
// deferred sum-reduce, cvt_pk P-pack, setprio ----------------
__global__ __launch_bounds__(256, 2) void k_attn(const unsigned short* __restrict__ qkv,
                                                 const unsigned short* __restrict__ vT,
                                                 unsigned short* __restrict__ o){
  __shared__ unsigned short Ks[2][64*128];   // 32KB, rows 256B, XOR-swizzled content
  __shared__ unsigned short VTs[2][128*64];  // 32KB, rows=d 128B, XOR-swizzled content
  __shared__ unsigned short Ps[4][2][16*64]; // 16KB, per-wave-per-qset P bridge
  int bh = blockIdx.y; int b = bh >> 3, h = bh & 7;
  int q0 = blockIdx.x * 128;
  int tid = threadIdx.x, lane = tid & 63, wave = tid >> 6;
  int cg = lane >> 4, cl = lane & 15;
  const unsigned short* base = qkv + (size_t)b*LSEQ*NQKV + h*HDIM;
  const unsigned short* kgl = base + DMODEL;
  const unsigned short* vtg = vT + (size_t)bh*HDIM*LSEQ;   // [d][l]

  // Q fragments (B-operand of swapped QK^T): two q-subtiles per wave
  short8 qf[2][4];
  #pragma unroll
  for (int qs=0;qs<2;++qs){
    const unsigned short* qr = base + (size_t)(q0 + wave*32 + qs*16 + cl)*NQKV;
    #pragma unroll
    for (int kk=0;kk<4;++kk) qf[qs][kk] = *(const short8*)(qr + kk*32 + cg*8);
  }

  const float K2 = 0.12753568849800323f;    // (1/sqrt(128)) * log2(e)
  float mrow[2] = {-3.0e38f, -3.0e38f}, lrow[2] = {0.f, 0.f};
  f32x4 zero = {0.f,0.f,0.f,0.f};
  f32x4 accO[2][8];
  #pragma unroll
  for (int qs=0;qs<2;++qs)
    #pragma unroll
    for (int dt=0;dt<8;++dt) accO[qs][dt] = zero;

  int keyc = (cl & 7) << 3;    // element-granular XOR key (P bridge + VT reads)

  // staging source decode
  int k_row4 = cg;                                  // K: row within 4-row chunk
  int v_dl   = lane >> 3;                           // VT: d within 8-row chunk
  int v_srcb = ((lane & 7)*16) ^ (v_dl << 4);       // VT: pre-swizzled byte col

  // ---- prologue: stage K(0), VT(0) into buf 0 ----
  #pragma unroll
  for (int j=0;j<4;++j){
    int ch = wave*4 + j;
    int row = ch*4 + k_row4;
    int srcb = (cl*16) ^ ((row & 7) << 4);
    gload_lds16(kgl + (size_t)row*NQKV + (srcb >> 1), (char*)Ks[0] + ch*1024);
  }
  #pragma unroll
  for (int j=0;j<4;++j){
    int ch = wave*4 + j;
    int d = ch*8 + v_dl;
    gload_lds16(vtg + (size_t)d*LSEQ + (v_srcb >> 1), (char*)VTs[0] + ch*1024);
  }

  const int NT = LSEQ/64;
  for (int t = 0; t < NT; ++t){
    int cur = t & 1;
    __syncthreads();   // drains tile-t gloads; guards buf[cur^1] overwrite

    // ---- issue K(t+1), VT(t+1) into alt buffers (in flight across compute) ----
    if (t+1 < NT){
      int kvn = (t+1)*64;
      #pragma unroll
      for (int j=0;j<4;++j){
        int ch = wave*4 + j;
        int row = ch*4 + k_row4;
        int srcb = (cl*16) ^ ((row & 7) << 4);
        gload_lds16(kgl + (size_t)(kvn+row)*NQKV + (srcb >> 1), (char*)Ks[cur^1] + ch*1024);
      }
      #pragma unroll
      for (int j=0;j<4;++j){
        int ch = wave*4 + j;
        int d = ch*8 + v_dl;
        gload_lds16(vtg + (size_t)d*LSEQ + kvn + (v_srcb >> 1), (char*)VTs[cur^1] + ch*1024);
      }
    }

    const char* kbuf = (const char*)Ks[cur];
    const unsigned short* vbuf = VTs[cur];

    // ---- QK^T swapped: S^T[kv][q]; each kf read feeds both q-subtiles ----
    f32x4 s[2][4];
    __builtin_amdgcn_s_setprio(1);
    #pragma unroll
    for (int nt=0;nt<4;++nt){
      f32x4 a0 = zero, a1 = zero;
      int rowb = (nt*16 + cl)*256;
      int key = (cl & 7) << 4;
      #pragma unroll
      for (int kkq=0;kkq<4;++kkq){
        short8 kf = *(const short8*)(kbuf + rowb + ((kkq*64 + cg*16) ^ key));
        a0 = __builtin_amdgcn_mfma_f32_16x16x32_bf16(kf, qf[0][kkq], a0, 0,0,0);
        a1 = __builtin_amdgcn_mfma_f32_16x16x32_bf16(kf, qf[1][kkq], a1, 0,0,0);
      }
      s[0][nt] = a0;
      s[1][nt] = a1;
    }
    __builtin_amdgcn_s_setprio(0);

    // ---- in-register online softmax, exp2 domain, defer-max (per q-set) ----
    #pragma unroll
    for (int qs=0;qs<2;++qs){
      float mx = s[qs][0][0];
      #pragma unroll
      for (int nt=0;nt<4;++nt)
        #pragma unroll
        for (int i=0;i<4;++i) mx = fmaxf(mx, s[qs][nt][i]);
      mx = fmaxf(mx, __shfl_xor(mx, 16));
      mx = fmaxf(mx, __shfl_xor(mx, 32));
      float mx2 = mx * K2;
      bool rescale = !__all(mx2 <= mrow[qs] + 11.5416f);   // THR = 8 nats
      float fac = 1.f;
      if (rescale){
        float mn = fmaxf(mrow[qs], mx2);
        fac = exp2f(mrow[qs] - mn);
        mrow[qs] = mn;
      }
      float sum = 0.f;
      #pragma unroll
      for (int nt=0;nt<4;++nt)
        #pragma unroll
        for (int i=0;i<4;++i){
          float e = exp2f(fmaf(s[qs][nt][i], K2, -mrow[qs]));
          s[qs][nt][i] = e;
          sum += e;
        }
      lrow[qs] = lrow[qs]*fac + sum;   // per-lane partial; reduced in epilogue
      if (rescale){
        float fq0 = __shfl(fac, (lane & 48) | (cg*4+0));
        float fq1 = __shfl(fac, (lane & 48) | (cg*4+1));
        float fq2 = __shfl(fac, (lane & 48) | (cg*4+2));
        float fq3 = __shfl(fac, (lane & 48) | (cg*4+3));
        #pragma unroll
        for (int dt=0;dt<8;++dt){
          f32x4 tv = accO[qs][dt];
          tv[0]*=fq0; tv[1]*=fq1; tv[2]*=fq2; tv[3]*=fq3;
          accO[qs][dt] = tv;
        }
      }
    }

    // ---- P pack via v_cvt_pk_bf16_f32, bridge through per-wave LDS ----
    short8 pa0[2], pa1[2];
    #pragma unroll
    for (int qs=0;qs<2;++qs){
      unsigned short* pw = &Ps[wave][qs][0];
      #pragma unroll
      for (int nt=0;nt<4;++nt){
        unsigned p01, p23;
        asm("v_cvt_pk_bf16_f32 %0, %1, %2" : "=v"(p01) : "v"(s[qs][nt][0]), "v"(s[qs][nt][1]));
        asm("v_cvt_pk_bf16_f32 %0, %1, %2" : "=v"(p23) : "v"(s[qs][nt][2]), "v"(s[qs][nt][3]));
        uint2 pk; pk.x = p01; pk.y = p23;
        *(uint2*)&pw[cl*64 + ((nt*16 + cg*4) ^ keyc)] = pk;   // kv = nt*16+cg*4+{0..3}
      }
      pa0[qs] = *(const short8*)&pw[cl*64 + ((cg*8)      ^ keyc)];  // kv = cg*8+e
      pa1[qs] = *(const short8*)&pw[cl*64 + ((32 + cg*8) ^ keyc)];  // kv = 32+cg*8+e
    }

    // ---- PV: each vf read feeds both q-subtiles ----
    __builtin_amdgcn_s_setprio(1);
    #pragma unroll
    for (int dt=0;dt<8;++dt){
      const unsigned short* vrow = &vbuf[(dt*16 + cl)*64];
      short8 vf0 = *(const short8*)&vrow[(cg*8)      ^ keyc];
      short8 vf1 = *(const short8*)&vrow[(32 + cg*8) ^ keyc];
      accO[0][dt] = __builtin_amdgcn_mfma_f32_16x16x32_bf16(pa0[0], vf0, accO[0][dt], 0,0,0);
      accO[0][dt] = __builtin_amdgcn_mfma_f32_16x16x32_bf16(pa1[0], vf1, accO[0][dt], 0,0,0);
      accO[1][dt] = __builtin_amdgcn_mfma_f32_16x16x32_bf16(pa0[1], vf0, accO[1][dt], 0,0,0);
      accO[1][dt] = __builtin_amdgcn_mfma_f32_16x16x32_bf16(pa1[1], vf1, accO[1][dt], 0,0,0);
    }
    __builtin_amdgcn_s_setprio(0);
  }

  // ---- epilogue (reduce deferred partial sums first) ----
  #pragma unroll
  for (int qs=0;qs<2;++qs){
    float lr = lrow[qs];
    lr += __shfl_xor(lr, 16);
    lr += __shfl_xor(lr, 32);
    float lq0 = __shfl(lr, (lane & 48) | (cg*4+0));
    float lq1 = __shfl(lr, (lane & 48) | (cg*4+1));
    float lq2 = __shfl(lr, (lane & 48) | (cg*4+2));
    float lq3 = __shfl(lr, (lane & 48) | (cg*4+3));
    float r0 = 1.f/lq0, r1 = 1.f/lq1, r2 = 1.f/lq2, r3 = 1.f/lq3;
    size_t orow = (size_t)(b*LSEQ + q0 + wave*32 + qs*16 + cg*4);
    #pragma unroll
    for (int dt=0;dt<8;++dt){
      int col = h*HDIM + dt*16 + cl;
      o[(orow+0)*DMODEL + col] = f2bf(accO[qs][dt][0]*r0);
      o[(orow+1)*DMODEL + col] = f2bf(accO[qs][dt][1]*r1);
      o[(orow+2)*DMODEL + col] = f2bf(accO[qs][dt][2]*r2);
      o[(orow+3)*DMODEL + col] = f2bf(accO[qs][dt][3]*r3);
    }
  }
}

extern "C" void kernel_launch(void* const* d_in, const int* in_sizes, int n_in,
                              void* d_out, int out_size, void* d_ws, size_t ws_size,
                              hipStream_t stream) {
  const float* x    = (const float*)d_in[0];
  const float* fcos = (const float*)d_in[1];
  const float* fsin = (const float*)d_in[2];
  const float* wqkv = (const float*)d_in[3];
  const float* bqkv = (const float*)d_in[4];
  const float* gq   = (const float*)d_in[5];
  const float* gk   = (const float*)d_in[6];
  const float* wout = (const float*)d_in[7];
  const float* bout = (const float*)d_in[8];
  float* out = (float*)d_out;

  char* ws = (char*)d_ws;
  unsigned short* xb    = (unsigned short*)(ws);                       // 16MB: x bf16, reused as vT
  unsigned short* qkv   = (unsigned short*)(ws + (16ull<<20));         // 48MB: qkv bf16
  unsigned short* ob    = (unsigned short*)(ws + (64ull<<20));         // 16MB: o bf16
  unsigned short* wqkvT = (unsigned short*)(ws + (80ull<<20));         // 6MB
  unsigned short* woutT = (unsigned short*)(ws + (86ull<<20));         // 2MB
  unsigned short* vT    = xb;                                          // alias: xb dead after GEMM1

  k_cvt<<<4096, 256, 0, stream>>>(x, xb, (MTOT*DMODEL)/8);
  k_transpose_cvt<<<dim3(96,32), 256, 0, stream>>>(wqkv, wqkvT, DMODEL, NQKV);
  k_transpose_cvt<<<dim3(32,32), 256, 0, stream>>>(wout, woutT, DMODEL, DMODEL);
  k_gemm_bt<1><<<dim3(NQKV/128, MTOT/128), 256, 0, stream>>>(xb, wqkvT, bqkv, qkv, MTOT, NQKV, DMODEL);
  k_norm_rope<<<MTOT, 256, 0, stream>>>(qkv, fcos, fsin, gq, gk);
  k_vT<<<dim3(LSEQ/32, HDIM/32, 16), 256, 0, stream>>>(qkv, vT);
  k_attn<<<dim3(LSEQ/128, 16), 256, 0, stream>>>(qkv, vT, ob);
  k_gemm_bt<0><<<dim3(DMODEL/128, MTOT/128), 256, 0, stream>>>(ob, woutT, bout, out, MTOT, DMODEL, DMODEL);
}

// Round 8
// 301.223 us; speedup vs baseline: 1.1785x; 1.0725x over previous
//
#include <hip/hip_runtime.h>
#include <hip/hip_bf16.h>
#include <stdint.h>

typedef __attribute__((ext_vector_type(8))) short short8;
typedef __attribute__((ext_vector_type(4))) short short4v;
typedef __attribute__((ext_vector_type(4))) float f32x4;
typedef __attribute__((ext_vector_type(16))) float f32x16;

#define LSEQ 4096
#define DMODEL 1024
#define NHEAD 8
#define HDIM 128
#define MTOT 8192
#define NQKV 3072

__device__ __forceinline__ unsigned short f2bf(float f){
  unsigned u = __float_as_uint(f);
  u += 0x7fffu + ((u >> 16) & 1u);
  return (unsigned short)(u >> 16);
}
__device__ __forceinline__ float bf2f(unsigned short h){
  return __uint_as_float(((unsigned)h) << 16);
}

typedef const __attribute__((address_space(1))) void* gas_ptr;
typedef __attribute__((address_space(3))) void* las_ptr;
__device__ __forceinline__ void gload_lds16(const void* g, void* l){
  __builtin_amdgcn_global_load_lds((gas_ptr)(uintptr_t)g,
                                   (las_ptr)(unsigned)(uintptr_t)l, 16, 0, 0);
}

// ---------------- fp32 -> bf16 cast (8 elems/thread) ----------------
__global__ __launch_bounds__(256) void k_cvt(const float* __restrict__ in,
                                             unsigned short* __restrict__ out, int n8){
  int i = blockIdx.x*256 + threadIdx.x;
  if (i >= n8) return;
  const float4* p = (const float4*)in + (size_t)i*2;
  float4 a = p[0], b = p[1];
  short8 r;
  r[0]=(short)f2bf(a.x); r[1]=(short)f2bf(a.y); r[2]=(short)f2bf(a.z); r[3]=(short)f2bf(a.w);
  r[4]=(short)f2bf(b.x); r[5]=(short)f2bf(b.y); r[6]=(short)f2bf(b.z); r[7]=(short)f2bf(b.w);
  *(short8*)(out + (size_t)i*8) = r;
}

// ---------------- fp32 [R][C] -> bf16 transposed [C][R] ----------------
__global__ __launch_bounds__(256) void k_transpose_cvt(const float* __restrict__ in,
                                                       unsigned short* __restrict__ out,
                                                       int R, int C){
  __shared__ unsigned short tile[32][33];
  int c0 = blockIdx.x*32, r0 = blockIdx.y*32;
  int tx = threadIdx.x & 31, ty = threadIdx.x >> 5;   // 32 x 8
  #pragma unroll
  for (int i=0;i<32;i+=8)
    tile[ty+i][tx] = f2bf(in[(size_t)(r0+ty+i)*C + c0+tx]);
  __syncthreads();
  #pragma unroll
  for (int i=0;i<32;i+=8)
    out[(size_t)(c0+ty+i)*R + r0+tx] = tile[tx][ty+i];
}

// ---------------- bf16 V -> V^T per head: vT[bh][d][l] ----------------
__global__ __launch_bounds__(256) void k_vT(const unsigned short* __restrict__ qkv,
                                            unsigned short* __restrict__ vT){
  __shared__ unsigned short tile[32][33];
  int bh = blockIdx.z; int b = bh >> 3, h = bh & 7;
  int l0 = blockIdx.x*32, d0 = blockIdx.y*32;
  const unsigned short* src = qkv + (size_t)b*LSEQ*NQKV + 2*DMODEL + h*HDIM;
  int tx = threadIdx.x & 31, ty = threadIdx.x >> 5;   // 32 x 8
  #pragma unroll
  for (int i=0;i<32;i+=8)
    tile[ty+i][tx] = src[(size_t)(l0+ty+i)*NQKV + d0+tx];
  __syncthreads();
  unsigned short* dst = vT + ((size_t)bh*HDIM + d0)*LSEQ + l0;
  #pragma unroll
  for (int i=0;i<32;i+=8)
    dst[(size_t)(ty+i)*LSEQ + tx] = tile[tx][ty+i];
}

// ---------------- bf16 GEMM: C[M][N] = A[M][K] * Bt[N][K]^T + bias ----------------
template<int OUT_BF16>
__global__ __launch_bounds__(256) void k_gemm_bt(const unsigned short* __restrict__ A,
                                                 const unsigned short* __restrict__ Bt,
                                                 const float* __restrict__ bias,
                                                 void* __restrict__ Cout,
                                                 int M, int N, int K){
  __shared__ unsigned short As[128*64];
  __shared__ unsigned short Bs[128*64];
  int tid = threadIdx.x, lane = tid & 63, wave = tid >> 6;
  int wm = wave >> 1, wn = wave & 1;
  int m0 = blockIdx.y*128, n0 = blockIdx.x*128;
  f32x4 zero = {0.f,0.f,0.f,0.f};
  f32x4 acc[4][4];
  #pragma unroll
  for (int mi=0;mi<4;++mi)
    #pragma unroll
    for (int ni=0;ni<4;++ni) acc[mi][ni] = zero;

  int srow = lane >> 3;
  int soffb = (lane & 7) * 16;
  int scol = (soffb ^ (srow << 4)) >> 1;
  int cg = lane >> 4, cl = lane & 15;

  int nkt = K >> 6;
  for (int kt = 0; kt < nkt; ++kt){
    if (kt) __syncthreads();
    int kbase = kt*64;
    #pragma unroll
    for (int j=0;j<4;++j){
      int ch = wave*4 + j;
      int row = ch*8 + srow;
      gload_lds16(A  + (size_t)(m0+row)*K + kbase + scol, (char*)As + ch*1024);
      gload_lds16(Bt + (size_t)(n0+row)*K + kbase + scol, (char*)Bs + ch*1024);
    }
    __syncthreads();

    short8 af[4][2], bf[4][2];
    #pragma unroll
    for (int mi=0;mi<4;++mi){
      int row = wm*64 + mi*16 + cl;
      int key = (row & 7) << 4;
      #pragma unroll
      for (int kk=0;kk<2;++kk)
        af[mi][kk] = *(const short8*)((const char*)As + row*128 + ((kk*64 + cg*16) ^ key));
    }
    #pragma unroll
    for (int ni=0;ni<4;++ni){
      int row = wn*64 + ni*16 + cl;
      int key = (row & 7) << 4;
      #pragma unroll
      for (int kk=0;kk<2;++kk)
        bf[ni][kk] = *(const short8*)((const char*)Bs + row*128 + ((kk*64 + cg*16) ^ key));
    }
    #pragma unroll
    for (int kk=0;kk<2;++kk)
      #pragma unroll
      for (int mi=0;mi<4;++mi)
        #pragma unroll
        for (int ni=0;ni<4;++ni)
          acc[mi][ni] = __builtin_amdgcn_mfma_f32_16x16x32_bf16(af[mi][kk], bf[ni][kk], acc[mi][ni], 0,0,0);
  }

  #pragma unroll
  for (int ni=0;ni<4;++ni){
    int col = n0 + wn*64 + ni*16 + cl;
    float bv = bias[col];
    #pragma unroll
    for (int mi=0;mi<4;++mi){
      int r = m0 + wm*64 + mi*16 + cg*4;
      #pragma unroll
      for (int i=0;i<4;++i){
        float v = acc[mi][ni][i] + bv;
        if (OUT_BF16) ((unsigned short*)Cout)[(size_t)(r+i)*N + col] = f2bf(v);
        else          ((float*)Cout)[(size_t)(r+i)*N + col] = v;
      }
    }
  }
}

// ---------------- fused RMSNorm(q,k) + interleaved RoPE ----------------
__global__ __launch_bounds__(256) void k_norm_rope(unsigned short* __restrict__ qkv,
                                                   const float* __restrict__ fcos,
                                                   const float* __restrict__ fsin,
                                                   const float* __restrict__ gq,
                                                   const float* __restrict__ gk){
  int bl = blockIdx.x;
  int l = bl & (LSEQ-1);
  int t = threadIdx.x;
  unsigned short* row = qkv + (size_t)bl * NQKV;
  int d0 = t*4;
  short4v qv = *(short4v*)(row + d0);
  short4v kv = *(short4v*)(row + DMODEL + d0);
  float q[4], k[4];
  #pragma unroll
  for (int j=0;j<4;++j){ q[j] = bf2f((unsigned short)qv[j]); k[j] = bf2f((unsigned short)kv[j]); }
  float sq = q[0]*q[0]+q[1]*q[1]+q[2]*q[2]+q[3]*q[3];
  float sk = k[0]*k[0]+k[1]*k[1]+k[2]*k[2]+k[3]*k[3];
  #pragma unroll
  for (int o=32;o;o>>=1){ sq += __shfl_xor(sq,o); sk += __shfl_xor(sk,o); }
  __shared__ float red[8];
  int lane = t & 63, wv = t >> 6;
  if (!lane){ red[wv] = sq; red[4+wv] = sk; }
  __syncthreads();
  sq = red[0]+red[1]+red[2]+red[3];
  sk = red[4]+red[5]+red[6]+red[7];
  float rq = rsqrtf(sq*(1.f/1024.f) + 1e-6f);
  float rk = rsqrtf(sk*(1.f/1024.f) + 1e-6f);
  int hd = d0 & (HDIM-1);
  int fi = (l << 6) + (hd >> 1);
  float c0 = fcos[fi], s0 = fsin[fi], c1 = fcos[fi+1], s1 = fsin[fi+1];
  {
    float x1 = q[0]*rq*gq[d0],   x2 = q[1]*rq*gq[d0+1];
    float x3 = q[2]*rq*gq[d0+2], x4 = q[3]*rq*gq[d0+3];
    short4v qo;
    qo[0]=(short)f2bf(x1*c0 - x2*s0); qo[1]=(short)f2bf(x1*s0 + x2*c0);
    qo[2]=(short)f2bf(x3*c1 - x4*s1); qo[3]=(short)f2bf(x3*s1 + x4*c1);
    *(short4v*)(row + d0) = qo;
  }
  {
    float x1 = k[0]*rk*gk[d0],   x2 = k[1]*rk*gk[d0+1];
    float x3 = k[2]*rk*gk[d0+2], x4 = k[3]*rk*gk[d0+3];
    short4v ko;
    ko[0]=(short)f2bf(x1*c0 - x2*s0); ko[1]=(short)f2bf(x1*s0 + x2*c0);
    ko[2]=(short)f2bf(x3*c1 - x4*s1); ko[3]=(short)f2bf(x3*s1 + x4*c1);
    *(short4v*)(row + DMODEL + d0) = ko;
  }
}

// ---------------- flash attention v8: 4 waves x 32 q-rows, 32x32x16 MFMA,
// in-register P via cvt_pk + permlane32_swap (no P LDS bridge), K+V^T staged
// via swizzled global_load_lds (dbuf), 1 barrier/tile, exp2 softmax + defer-max ----
__global__ __launch_bounds__(256, 2) void k_attn(const unsigned short* __restrict__ qkv,
                                                 const unsigned short* __restrict__ vT,
                                                 unsigned short* __restrict__ o){
  __shared__ unsigned short Ks[2][64*128];   // 32KB, rows 256B, XOR-swizzled content
  __shared__ unsigned short VTs[2][128*64];  // 32KB, rows=d 128B, XOR-swizzled content
  int bh = blockIdx.y; int b = bh >> 3, h = bh & 7;
  int q0 = blockIdx.x * 128;
  int tid = threadIdx.x, lane = tid & 63, wave = tid >> 6;
  int ql = lane & 31, hf = lane >> 5;
  const unsigned short* base = qkv + (size_t)b*LSEQ*NQKV + h*HDIM;
  const unsigned short* kgl = base + DMODEL;
  const unsigned short* vtg = vT + (size_t)bh*HDIM*LSEQ;   // [d][l]

  // Q B-frags: lane holds Q[q = ql][d = st*16 + hf*8 + e], st=0..7
  short8 qf[8];
  {
    const unsigned short* qr = base + (size_t)(q0 + wave*32 + ql)*NQKV + hf*8;
    #pragma unroll
    for (int st=0;st<8;++st) qf[st] = *(const short8*)(qr + st*16);
  }

  const float K2 = 0.12753568849800323f;    // (1/sqrt(128)) * log2(e)
  float mrow = -3.0e38f, lrow = 0.f;
  f32x16 z16 = {0.f};
  f32x16 acc[4];
  acc[0]=z16; acc[1]=z16; acc[2]=z16; acc[3]=z16;

  int key = (ql & 7) << 4;     // byte XOR key (K rows ql/ql+32 and V rows dt*32+ql share it)

  // staging source decode (R7-proven)
  int k_row4 = lane >> 4;                           // unused placeholder
  (void)k_row4;
  int v_dl   = lane >> 3;                           // VT: d within 8-row chunk
  int v_srcb = ((lane & 7)*16) ^ (v_dl << 4);       // VT: pre-swizzled byte col
  int cgk = (lane >> 4) & 3;                        // K: 4-row chunk sub-row

  // ---- prologue: stage K(0), VT(0) into buf 0 ----
  #pragma unroll
  for (int j=0;j<4;++j){
    int ch = wave*4 + j;
    int row = ch*4 + cgk;
    int srcb = ((lane & 15)*16) ^ ((row & 7) << 4);
    gload_lds16(kgl + (size_t)row*NQKV + (srcb >> 1), (char*)Ks[0] + ch*1024);
  }
  #pragma unroll
  for (int j=0;j<4;++j){
    int ch = wave*4 + j;
    int d = ch*8 + v_dl;
    gload_lds16(vtg + (size_t)d*LSEQ + (v_srcb >> 1), (char*)VTs[0] + ch*1024);
  }

  const int NT = LSEQ/64;
  for (int t = 0; t < NT; ++t){
    int cur = t & 1;
    __syncthreads();   // drains tile-t gloads; guards buf[cur^1] overwrite

    // ---- issue K(t+1), VT(t+1) into alt buffers (in flight across compute) ----
    if (t+1 < NT){
      int kvn = (t+1)*64;
      #pragma unroll
      for (int j=0;j<4;++j){
        int ch = wave*4 + j;
        int row = ch*4 + cgk;
        int srcb = ((lane & 15)*16) ^ ((row & 7) << 4);
        gload_lds16(kgl + (size_t)(kvn+row)*NQKV + (srcb >> 1), (char*)Ks[cur^1] + ch*1024);
      }
      #pragma unroll
      for (int j=0;j<4;++j){
        int ch = wave*4 + j;
        int d = ch*8 + v_dl;
        gload_lds16(vtg + (size_t)d*LSEQ + kvn + (v_srcb >> 1), (char*)VTs[cur^1] + ch*1024);
      }
    }

    const char* kb = (const char*)Ks[cur];
    const char* vb = (const char*)VTs[cur];

    // ---- QK^T swapped: S^T[kv][q] = mfma32(K, Q); lane: q=ql, kv rows ----
    f32x16 s0 = z16, s1 = z16;
    __builtin_amdgcn_s_setprio(1);
    #pragma unroll
    for (int st=0;st<8;++st){
      int col = (hf*16 + st*32) ^ key;
      short8 kf0 = *(const short8*)(kb + ql*256 + col);          // kv rows 0-31
      short8 kf1 = *(const short8*)(kb + ql*256 + 8192 + col);   // kv rows 32-63
      s0 = __builtin_amdgcn_mfma_f32_32x32x16_bf16(kf0, qf[st], s0, 0,0,0);
      s1 = __builtin_amdgcn_mfma_f32_32x32x16_bf16(kf1, qf[st], s1, 0,0,0);
    }
    __builtin_amdgcn_s_setprio(0);

    // ---- in-register online softmax, exp2 domain, defer-max ----
    float mx = s0[0];
    #pragma unroll
    for (int i=1;i<16;++i) mx = fmaxf(mx, s0[i]);
    #pragma unroll
    for (int i=0;i<16;++i) mx = fmaxf(mx, s1[i]);
    mx = fmaxf(mx, __shfl_xor(mx, 32));
    float mx2 = mx * K2;
    bool rescale = !__all(mx2 <= mrow + 11.5416f);   // THR = 8 nats
    if (rescale){
      float mn = fmaxf(mrow, mx2);
      float fac = exp2f(mrow - mn);
      mrow = mn;
      lrow *= fac;
      // per-row factors: row q = (r&3) + 8*(r>>2) + 4*hf
      float fr[16];
      #pragma unroll
      for (int r=0;r<16;++r) fr[r] = __shfl(fac, (r&3) + 8*(r>>2) + 4*hf);
      #pragma unroll
      for (int dt=0;dt<4;++dt)
        #pragma unroll
        for (int r=0;r<16;++r) acc[dt][r] *= fr[r];
    }
    float sum = 0.f;
    #pragma unroll
    for (int i=0;i<16;++i){
      float e = exp2f(fmaf(s0[i], K2, -mrow));
      s0[i] = e; sum += e;
    }
    #pragma unroll
    for (int i=0;i<16;++i){
      float e = exp2f(fmaf(s1[i], K2, -mrow));
      s1[i] = e; sum += e;
    }
    lrow += sum;   // per-lane partial (this lane's 32 kv); xor-32 reduced in epilogue

    // ---- P -> A-frags in-register (cvt_pk + permlane32_swap), then PV ----
    __builtin_amdgcn_s_setprio(1);
    #pragma unroll
    for (int c=0;c<4;++c){
      unsigned c01, c23, c45, c67;
      if (c < 2){
        int rb = (c&1)*8;
        asm("v_cvt_pk_bf16_f32 %0, %1, %2" : "=v"(c01) : "v"(s0[rb+0]), "v"(s0[rb+1]));
        asm("v_cvt_pk_bf16_f32 %0, %1, %2" : "=v"(c23) : "v"(s0[rb+2]), "v"(s0[rb+3]));
        asm("v_cvt_pk_bf16_f32 %0, %1, %2" : "=v"(c45) : "v"(s0[rb+4]), "v"(s0[rb+5]));
        asm("v_cvt_pk_bf16_f32 %0, %1, %2" : "=v"(c67) : "v"(s0[rb+6]), "v"(s0[rb+7]));
      } else {
        int rb = (c&1)*8;
        asm("v_cvt_pk_bf16_f32 %0, %1, %2" : "=v"(c01) : "v"(s1[rb+0]), "v"(s1[rb+1]));
        asm("v_cvt_pk_bf16_f32 %0, %1, %2" : "=v"(c23) : "v"(s1[rb+2]), "v"(s1[rb+3]));
        asm("v_cvt_pk_bf16_f32 %0, %1, %2" : "=v"(c45) : "v"(s1[rb+4]), "v"(s1[rb+5]));
        asm("v_cvt_pk_bf16_f32 %0, %1, %2" : "=v"(c67) : "v"(s1[rb+6]), "v"(s1[rb+7]));
      }
      // swap: c01.hi <-> c45.lo ; c23.hi <-> c67.lo
      asm("v_permlane32_swap_b32 %0, %1" : "+v"(c01), "+v"(c45));
      asm("v_permlane32_swap_b32 %0, %1" : "+v"(c23), "+v"(c67));
      union { unsigned u[4]; short8 v; } pu;
      pu.u[0] = c01; pu.u[1] = c23; pu.u[2] = c45; pu.u[3] = c67;
      short8 pa = pu.v;   // A[q=ql][kv = c*16 + hf*8 + e]
      #pragma unroll
      for (int dt=0;dt<4;++dt){
        int col = (c*32 + hf*16) ^ key;
        short8 vf = *(const short8*)(vb + (dt*32 + ql)*128 + col);
        acc[dt] = __builtin_amdgcn_mfma_f32_32x32x16_bf16(pa, vf, acc[dt], 0,0,0);
      }
    }
    __builtin_amdgcn_s_setprio(0);
  }

  // ---- epilogue ----
  lrow += __shfl_xor(lrow, 32);
  float rl = 1.f / lrow;       // per q = ql
  float rr[16];
  #pragma unroll
  for (int r=0;r<16;++r) rr[r] = __shfl(rl, (r&3) + 8*(r>>2) + 4*hf);
  size_t qbase = (size_t)(b*LSEQ + q0 + wave*32);
  #pragma unroll
  for (int dt=0;dt<4;++dt){
    int col = h*HDIM + dt*32 + ql;
    #pragma unroll
    for (int r=0;r<16;++r){
      int qrow = (r&3) + 8*(r>>2) + 4*hf;
      o[(qbase + qrow)*DMODEL + col] = f2bf(acc[dt][r]*rr[r]);
    }
  }
}

extern "C" void kernel_launch(void* const* d_in, const int* in_sizes, int n_in,
                              void* d_out, int out_size, void* d_ws, size_t ws_size,
                              hipStream_t stream) {
  const float* x    = (const float*)d_in[0];
  const float* fcos = (const float*)d_in[1];
  const float* fsin = (const float*)d_in[2];
  const float* wqkv = (const float*)d_in[3];
  const float* bqkv = (const float*)d_in[4];
  const float* gq   = (const float*)d_in[5];
  const float* gk   = (const float*)d_in[6];
  const float* wout = (const float*)d_in[7];
  const float* bout = (const float*)d_in[8];
  float* out = (float*)d_out;

  char* ws = (char*)d_ws;
  unsigned short* xb    = (unsigned short*)(ws);                       // 16MB: x bf16, reused as vT
  unsigned short* qkv   = (unsigned short*)(ws + (16ull<<20));         // 48MB: qkv bf16
  unsigned short* ob    = (unsigned short*)(ws + (64ull<<20));         // 16MB: o bf16
  unsigned short* wqkvT = (unsigned short*)(ws + (80ull<<20));         // 6MB
  unsigned short* woutT = (unsigned short*)(ws + (86ull<<20));         // 2MB
  unsigned short* vT    = xb;                                          // alias: xb dead after GEMM1

  k_cvt<<<4096, 256, 0, stream>>>(x, xb, (MTOT*DMODEL)/8);
  k_transpose_cvt<<<dim3(96,32), 256, 0, stream>>>(wqkv, wqkvT, DMODEL, NQKV);
  k_transpose_cvt<<<dim3(32,32), 256, 0, stream>>>(wout, woutT, DMODEL, DMODEL);
  k_gemm_bt<1><<<dim3(NQKV/128, MTOT/128), 256, 0, stream>>>(xb, wqkvT, bqkv, qkv, MTOT, NQKV, DMODEL);
  k_norm_rope<<<MTOT, 256, 0, stream>>>(qkv, fcos, fsin, gq, gk);
  k_vT<<<dim3(LSEQ/32, HDIM/32, 16), 256, 0, stream>>>(qkv, vT);
  k_attn<<<dim3(LSEQ/128, 16), 256, 0, stream>>>(qkv, vT, ob);
  k_gemm_bt<0><<<dim3(DMODEL/128, MTOT/128), 256, 0, stream>>>(ob, woutT, bout, out, MTOT, DMODEL, DMODEL);
}

// Round 9
// 294.613 us; speedup vs baseline: 1.2049x; 1.0224x over previous
//
#include <hip/hip_runtime.h>
#include <hip/hip_bf16.h>
#include <stdint.h>

typedef __attribute__((ext_vector_type(8))) short short8;
typedef __attribute__((ext_vector_type(4))) short short4v;
typedef __attribute__((ext_vector_type(4))) float f32x4;
typedef __attribute__((ext_vector_type(16))) float f32x16;

#define LSEQ 4096
#define DMODEL 1024
#define NHEAD 8
#define HDIM 128
#define MTOT 8192
#define NQKV 3072

__device__ __forceinline__ unsigned short f2bf(float f){
  unsigned u = __float_as_uint(f);
  u += 0x7fffu + ((u >> 16) & 1u);
  return (unsigned short)(u >> 16);
}
__device__ __forceinline__ float bf2f(unsigned short h){
  return __uint_as_float(((unsigned)h) << 16);
}
__device__ __forceinline__ float max3f(float a, float b, float c){
  float d;
  asm("v_max3_f32 %0, %1, %2, %3" : "=v"(d) : "v"(a), "v"(b), "v"(c));
  return d;
}

typedef const __attribute__((address_space(1))) void* gas_ptr;
typedef __attribute__((address_space(3))) void* las_ptr;
__device__ __forceinline__ void gload_lds16(const void* g, void* l){
  __builtin_amdgcn_global_load_lds((gas_ptr)(uintptr_t)g,
                                   (las_ptr)(unsigned)(uintptr_t)l, 16, 0, 0);
}

// ---------------- fp32 -> bf16 cast (8 elems/thread) ----------------
__global__ __launch_bounds__(256) void k_cvt(const float* __restrict__ in,
                                             unsigned short* __restrict__ out, int n8){
  int i = blockIdx.x*256 + threadIdx.x;
  if (i >= n8) return;
  const float4* p = (const float4*)in + (size_t)i*2;
  float4 a = p[0], b = p[1];
  short8 r;
  r[0]=(short)f2bf(a.x); r[1]=(short)f2bf(a.y); r[2]=(short)f2bf(a.z); r[3]=(short)f2bf(a.w);
  r[4]=(short)f2bf(b.x); r[5]=(short)f2bf(b.y); r[6]=(short)f2bf(b.z); r[7]=(short)f2bf(b.w);
  *(short8*)(out + (size_t)i*8) = r;
}

// ---------------- fp32 [R][C] -> bf16 transposed [C][R] ----------------
__global__ __launch_bounds__(256) void k_transpose_cvt(const float* __restrict__ in,
                                                       unsigned short* __restrict__ out,
                                                       int R, int C){
  __shared__ unsigned short tile[32][33];
  int c0 = blockIdx.x*32, r0 = blockIdx.y*32;
  int tx = threadIdx.x & 31, ty = threadIdx.x >> 5;   // 32 x 8
  #pragma unroll
  for (int i=0;i<32;i+=8)
    tile[ty+i][tx] = f2bf(in[(size_t)(r0+ty+i)*C + c0+tx]);
  __syncthreads();
  #pragma unroll
  for (int i=0;i<32;i+=8)
    out[(size_t)(c0+ty+i)*R + r0+tx] = tile[tx][ty+i];
}

// ---------------- bf16 V -> V^T per head: vT[bh][d][l] ----------------
__global__ __launch_bounds__(256) void k_vT(const unsigned short* __restrict__ qkv,
                                            unsigned short* __restrict__ vT){
  __shared__ unsigned short tile[32][33];
  int bh = blockIdx.z; int b = bh >> 3, h = bh & 7;
  int l0 = blockIdx.x*32, d0 = blockIdx.y*32;
  const unsigned short* src = qkv + (size_t)b*LSEQ*NQKV + 2*DMODEL + h*HDIM;
  int tx = threadIdx.x & 31, ty = threadIdx.x >> 5;   // 32 x 8
  #pragma unroll
  for (int i=0;i<32;i+=8)
    tile[ty+i][tx] = src[(size_t)(l0+ty+i)*NQKV + d0+tx];
  __syncthreads();
  unsigned short* dst = vT + ((size_t)bh*HDIM + d0)*LSEQ + l0;
  #pragma unroll
  for (int i=0;i<32;i+=8)
    dst[(size_t)(ty+i)*LSEQ + tx] = tile[tx][ty+i];
}

// ---------------- bf16 GEMM: C[M][N] = A[M][K] * Bt[N][K]^T + bias ----------------
template<int OUT_BF16>
__global__ __launch_bounds__(256) void k_gemm_bt(const unsigned short* __restrict__ A,
                                                 const unsigned short* __restrict__ Bt,
                                                 const float* __restrict__ bias,
                                                 void* __restrict__ Cout,
                                                 int M, int N, int K){
  __shared__ unsigned short As[128*64];
  __shared__ unsigned short Bs[128*64];
  int tid = threadIdx.x, lane = tid & 63, wave = tid >> 6;
  int wm = wave >> 1, wn = wave & 1;
  int m0 = blockIdx.y*128, n0 = blockIdx.x*128;
  f32x4 zero = {0.f,0.f,0.f,0.f};
  f32x4 acc[4][4];
  #pragma unroll
  for (int mi=0;mi<4;++mi)
    #pragma unroll
    for (int ni=0;ni<4;++ni) acc[mi][ni] = zero;

  int srow = lane >> 3;
  int soffb = (lane & 7) * 16;
  int scol = (soffb ^ (srow << 4)) >> 1;
  int cg = lane >> 4, cl = lane & 15;

  int nkt = K >> 6;
  for (int kt = 0; kt < nkt; ++kt){
    if (kt) __syncthreads();
    int kbase = kt*64;
    #pragma unroll
    for (int j=0;j<4;++j){
      int ch = wave*4 + j;
      int row = ch*8 + srow;
      gload_lds16(A  + (size_t)(m0+row)*K + kbase + scol, (char*)As + ch*1024);
      gload_lds16(Bt + (size_t)(n0+row)*K + kbase + scol, (char*)Bs + ch*1024);
    }
    __syncthreads();

    short8 af[4][2], bf[4][2];
    #pragma unroll
    for (int mi=0;mi<4;++mi){
      int row = wm*64 + mi*16 + cl;
      int key = (row & 7) << 4;
      #pragma unroll
      for (int kk=0;kk<2;++kk)
        af[mi][kk] = *(const short8*)((const char*)As + row*128 + ((kk*64 + cg*16) ^ key));
    }
    #pragma unroll
    for (int ni=0;ni<4;++ni){
      int row = wn*64 + ni*16 + cl;
      int key = (row & 7) << 4;
      #pragma unroll
      for (int kk=0;kk<2;++kk)
        bf[ni][kk] = *(const short8*)((const char*)Bs + row*128 + ((kk*64 + cg*16) ^ key));
    }
    #pragma unroll
    for (int kk=0;kk<2;++kk)
      #pragma unroll
      for (int mi=0;mi<4;++mi)
        #pragma unroll
        for (int ni=0;ni<4;++ni)
          acc[mi][ni] = __builtin_amdgcn_mfma_f32_16x16x32_bf16(af[mi][kk], bf[ni][kk], acc[mi][ni], 0,0,0);
  }

  #pragma unroll
  for (int ni=0;ni<4;++ni){
    int col = n0 + wn*64 + ni*16 + cl;
    float bv = bias[col];
    #pragma unroll
    for (int mi=0;mi<4;++mi){
      int r = m0 + wm*64 + mi*16 + cg*4;
      #pragma unroll
      for (int i=0;i<4;++i){
        float v = acc[mi][ni][i] + bv;
        if (OUT_BF16) ((unsigned short*)Cout)[(size_t)(r+i)*N + col] = f2bf(v);
        else          ((float*)Cout)[(size_t)(r+i)*N + col] = v;
      }
    }
  }
}

// ---------------- fused RMSNorm(q,k) + interleaved RoPE ----------------
__global__ __launch_bounds__(256) void k_norm_rope(unsigned short* __restrict__ qkv,
                                                   const float* __restrict__ fcos,
                                                   const float* __restrict__ fsin,
                                                   const float* __restrict__ gq,
                                                   const float* __restrict__ gk){
  int bl = blockIdx.x;
  int l = bl & (LSEQ-1);
  int t = threadIdx.x;
  unsigned short* row = qkv + (size_t)bl * NQKV;
  int d0 = t*4;
  short4v qv = *(short4v*)(row + d0);
  short4v kv = *(short4v*)(row + DMODEL + d0);
  float q[4], k[4];
  #pragma unroll
  for (int j=0;j<4;++j){ q[j] = bf2f((unsigned short)qv[j]); k[j] = bf2f((unsigned short)kv[j]); }
  float sq = q[0]*q[0]+q[1]*q[1]+q[2]*q[2]+q[3]*q[3];
  float sk = k[0]*k[0]+k[1]*k[1]+k[2]*k[2]+k[3]*k[3];
  #pragma unroll
  for (int o=32;o;o>>=1){ sq += __shfl_xor(sq,o); sk += __shfl_xor(sk,o); }
  __shared__ float red[8];
  int lane = t & 63, wv = t >> 6;
  if (!lane){ red[wv] = sq; red[4+wv] = sk; }
  __syncthreads();
  sq = red[0]+red[1]+red[2]+red[3];
  sk = red[4]+red[5]+red[6]+red[7];
  float rq = rsqrtf(sq*(1.f/1024.f) + 1e-6f);
  float rk = rsqrtf(sk*(1.f/1024.f) + 1e-6f);
  int hd = d0 & (HDIM-1);
  int fi = (l << 6) + (hd >> 1);
  float c0 = fcos[fi], s0 = fsin[fi], c1 = fcos[fi+1], s1 = fsin[fi+1];
  {
    float x1 = q[0]*rq*gq[d0],   x2 = q[1]*rq*gq[d0+1];
    float x3 = q[2]*rq*gq[d0+2], x4 = q[3]*rq*gq[d0+3];
    short4v qo;
    qo[0]=(short)f2bf(x1*c0 - x2*s0); qo[1]=(short)f2bf(x1*s0 + x2*c0);
    qo[2]=(short)f2bf(x3*c1 - x4*s1); qo[3]=(short)f2bf(x3*s1 + x4*c1);
    *(short4v*)(row + d0) = qo;
  }
  {
    float x1 = k[0]*rk*gk[d0],   x2 = k[1]*rk*gk[d0+1];
    float x3 = k[2]*rk*gk[d0+2], x4 = k[3]*rk*gk[d0+3];
    short4v ko;
    ko[0]=(short)f2bf(x1*c0 - x2*s0); ko[1]=(short)f2bf(x1*s0 + x2*c0);
    ko[2]=(short)f2bf(x3*c1 - x4*s1); ko[3]=(short)f2bf(x3*s1 + x4*c1);
    *(short4v*)(row + DMODEL + d0) = ko;
  }
}

// ---------------- flash attention v9: v8 + row-sum via MFMA-ones (no per-lane
// sum adds, no epilogue shuffles) + v_max3 row-max tree ----------------
__global__ __launch_bounds__(256, 2) void k_attn(const unsigned short* __restrict__ qkv,
                                                 const unsigned short* __restrict__ vT,
                                                 unsigned short* __restrict__ o){
  __shared__ unsigned short Ks[2][64*128];   // 32KB, rows 256B, XOR-swizzled content
  __shared__ unsigned short VTs[2][128*64];  // 32KB, rows=d 128B, XOR-swizzled content
  int bh = blockIdx.y; int b = bh >> 3, h = bh & 7;
  int q0 = blockIdx.x * 128;
  int tid = threadIdx.x, lane = tid & 63, wave = tid >> 6;
  int ql = lane & 31, hf = lane >> 5;
  const unsigned short* base = qkv + (size_t)b*LSEQ*NQKV + h*HDIM;
  const unsigned short* kgl = base + DMODEL;
  const unsigned short* vtg = vT + (size_t)bh*HDIM*LSEQ;   // [d][l]

  // Q B-frags: lane holds Q[q = ql][d = st*16 + hf*8 + e], st=0..7
  short8 qf[8];
  {
    const unsigned short* qr = base + (size_t)(q0 + wave*32 + ql)*NQKV + hf*8;
    #pragma unroll
    for (int st=0;st<8;++st) qf[st] = *(const short8*)(qr + st*16);
  }
  short8 ones;
  #pragma unroll
  for (int j=0;j<8;++j) ones[j] = (short)0x3F80;   // bf16 1.0

  const float K2 = 0.12753568849800323f;    // (1/sqrt(128)) * log2(e)
  float mrow = -3.0e38f;
  f32x16 z16 = {0.f};
  f32x16 acc[4];
  acc[0]=z16; acc[1]=z16; acc[2]=z16; acc[3]=z16;
  f32x16 accl = z16;                         // row-sums l (MFMA-ones)

  int key = (ql & 7) << 4;     // byte XOR key (K rows ql/ql+32 and V rows dt*32+ql share it)

  int v_dl   = lane >> 3;                           // VT: d within 8-row chunk
  int v_srcb = ((lane & 7)*16) ^ (v_dl << 4);       // VT: pre-swizzled byte col
  int cgk = (lane >> 4) & 3;                        // K: 4-row chunk sub-row

  // ---- prologue: stage K(0), VT(0) into buf 0 ----
  #pragma unroll
  for (int j=0;j<4;++j){
    int ch = wave*4 + j;
    int row = ch*4 + cgk;
    int srcb = ((lane & 15)*16) ^ ((row & 7) << 4);
    gload_lds16(kgl + (size_t)row*NQKV + (srcb >> 1), (char*)Ks[0] + ch*1024);
  }
  #pragma unroll
  for (int j=0;j<4;++j){
    int ch = wave*4 + j;
    int d = ch*8 + v_dl;
    gload_lds16(vtg + (size_t)d*LSEQ + (v_srcb >> 1), (char*)VTs[0] + ch*1024);
  }

  const int NT = LSEQ/64;
  for (int t = 0; t < NT; ++t){
    int cur = t & 1;
    __syncthreads();   // drains tile-t gloads; guards buf[cur^1] overwrite

    // ---- issue K(t+1), VT(t+1) into alt buffers (in flight across compute) ----
    if (t+1 < NT){
      int kvn = (t+1)*64;
      #pragma unroll
      for (int j=0;j<4;++j){
        int ch = wave*4 + j;
        int row = ch*4 + cgk;
        int srcb = ((lane & 15)*16) ^ ((row & 7) << 4);
        gload_lds16(kgl + (size_t)(kvn+row)*NQKV + (srcb >> 1), (char*)Ks[cur^1] + ch*1024);
      }
      #pragma unroll
      for (int j=0;j<4;++j){
        int ch = wave*4 + j;
        int d = ch*8 + v_dl;
        gload_lds16(vtg + (size_t)d*LSEQ + kvn + (v_srcb >> 1), (char*)VTs[cur^1] + ch*1024);
      }
    }

    const char* kb = (const char*)Ks[cur];
    const char* vb = (const char*)VTs[cur];

    // ---- QK^T swapped: S^T[kv][q] = mfma32(K, Q); lane: q=ql, kv rows ----
    f32x16 s0 = z16, s1 = z16;
    __builtin_amdgcn_s_setprio(1);
    #pragma unroll
    for (int st=0;st<8;++st){
      int col = (hf*16 + st*32) ^ key;
      short8 kf0 = *(const short8*)(kb + ql*256 + col);          // kv rows 0-31
      short8 kf1 = *(const short8*)(kb + ql*256 + 8192 + col);   // kv rows 32-63
      s0 = __builtin_amdgcn_mfma_f32_32x32x16_bf16(kf0, qf[st], s0, 0,0,0);
      s1 = __builtin_amdgcn_mfma_f32_32x32x16_bf16(kf1, qf[st], s1, 0,0,0);
    }
    __builtin_amdgcn_s_setprio(0);

    // ---- row max via v_max3 tree (32 values -> 16 instrs) ----
    float t10[10];
    #pragma unroll
    for (int j=0;j<5;++j)  t10[j]   = max3f(s0[3*j], s0[3*j+1], s0[3*j+2]);
    t10[5] = max3f(s0[15], s1[0], s1[1]);
    #pragma unroll
    for (int j=0;j<4;++j)  t10[6+j] = max3f(s1[2+3*j], s1[3+3*j], s1[4+3*j]);
    float u0 = max3f(t10[0], t10[1], t10[2]);
    float u1 = max3f(t10[3], t10[4], t10[5]);
    float u2 = max3f(t10[6], t10[7], t10[8]);
    float u3 = max3f(t10[9], s1[14], s1[15]);
    float mx = fmaxf(fmaxf(u0,u1), fmaxf(u2,u3));
    mx = fmaxf(mx, __shfl_xor(mx, 32));

    // ---- online softmax, exp2 domain, defer-max ----
    float mx2 = mx * K2;
    bool rescale = !__all(mx2 <= mrow + 11.5416f);   // THR = 8 nats
    if (rescale){
      float mn = fmaxf(mrow, mx2);
      float fac = exp2f(mrow - mn);
      mrow = mn;
      float fr[16];
      #pragma unroll
      for (int r=0;r<16;++r) fr[r] = __shfl(fac, (r&3) + 8*(r>>2) + 4*hf);
      #pragma unroll
      for (int dt=0;dt<4;++dt)
        #pragma unroll
        for (int r=0;r<16;++r) acc[dt][r] *= fr[r];
      #pragma unroll
      for (int r=0;r<16;++r) accl[r] *= fr[r];
    }
    #pragma unroll
    for (int i=0;i<16;++i) s0[i] = exp2f(fmaf(s0[i], K2, -mrow));
    #pragma unroll
    for (int i=0;i<16;++i) s1[i] = exp2f(fmaf(s1[i], K2, -mrow));

    // ---- P -> A-frags in-register (cvt_pk + permlane32_swap), then PV + l ----
    __builtin_amdgcn_s_setprio(1);
    #pragma unroll
    for (int c=0;c<4;++c){
      unsigned c01, c23, c45, c67;
      if (c < 2){
        int rb = (c&1)*8;
        asm("v_cvt_pk_bf16_f32 %0, %1, %2" : "=v"(c01) : "v"(s0[rb+0]), "v"(s0[rb+1]));
        asm("v_cvt_pk_bf16_f32 %0, %1, %2" : "=v"(c23) : "v"(s0[rb+2]), "v"(s0[rb+3]));
        asm("v_cvt_pk_bf16_f32 %0, %1, %2" : "=v"(c45) : "v"(s0[rb+4]), "v"(s0[rb+5]));
        asm("v_cvt_pk_bf16_f32 %0, %1, %2" : "=v"(c67) : "v"(s0[rb+6]), "v"(s0[rb+7]));
      } else {
        int rb = (c&1)*8;
        asm("v_cvt_pk_bf16_f32 %0, %1, %2" : "=v"(c01) : "v"(s1[rb+0]), "v"(s1[rb+1]));
        asm("v_cvt_pk_bf16_f32 %0, %1, %2" : "=v"(c23) : "v"(s1[rb+2]), "v"(s1[rb+3]));
        asm("v_cvt_pk_bf16_f32 %0, %1, %2" : "=v"(c45) : "v"(s1[rb+4]), "v"(s1[rb+5]));
        asm("v_cvt_pk_bf16_f32 %0, %1, %2" : "=v"(c67) : "v"(s1[rb+6]), "v"(s1[rb+7]));
      }
      // swap: c01.hi <-> c45.lo ; c23.hi <-> c67.lo
      asm("v_permlane32_swap_b32 %0, %1" : "+v"(c01), "+v"(c45));
      asm("v_permlane32_swap_b32 %0, %1" : "+v"(c23), "+v"(c67));
      union { unsigned u[4]; short8 v; } pu;
      pu.u[0] = c01; pu.u[1] = c23; pu.u[2] = c45; pu.u[3] = c67;
      short8 pa = pu.v;   // A[q=ql][kv = c*16 + hf*8 + e]
      accl = __builtin_amdgcn_mfma_f32_32x32x16_bf16(pa, ones, accl, 0,0,0);
      #pragma unroll
      for (int dt=0;dt<4;++dt){
        int col = (c*32 + hf*16) ^ key;
        short8 vf = *(const short8*)(vb + (dt*32 + ql)*128 + col);
        acc[dt] = __builtin_amdgcn_mfma_f32_32x32x16_bf16(pa, vf, acc[dt], 0,0,0);
      }
    }
    __builtin_amdgcn_s_setprio(0);
  }

  // ---- epilogue: accl[r] holds l for q-row rowmap(r) (all lanes) ----
  float rr[16];
  #pragma unroll
  for (int r=0;r<16;++r) rr[r] = 1.f / accl[r];
  size_t qbase = (size_t)(b*LSEQ + q0 + wave*32);
  #pragma unroll
  for (int dt=0;dt<4;++dt){
    int col = h*HDIM + dt*32 + ql;
    #pragma unroll
    for (int r=0;r<16;++r){
      int qrow = (r&3) + 8*(r>>2) + 4*hf;
      o[(qbase + qrow)*DMODEL + col] = f2bf(acc[dt][r]*rr[r]);
    }
  }
}

extern "C" void kernel_launch(void* const* d_in, const int* in_sizes, int n_in,
                              void* d_out, int out_size, void* d_ws, size_t ws_size,
                              hipStream_t stream) {
  const float* x    = (const float*)d_in[0];
  const float* fcos = (const float*)d_in[1];
  const float* fsin = (const float*)d_in[2];
  const float* wqkv = (const float*)d_in[3];
  const float* bqkv = (const float*)d_in[4];
  const float* gq   = (const float*)d_in[5];
  const float* gk   = (const float*)d_in[6];
  const float* wout = (const float*)d_in[7];
  const float* bout = (const float*)d_in[8];
  float* out = (float*)d_out;

  char* ws = (char*)d_ws;
  unsigned short* xb    = (unsigned short*)(ws);                       // 16MB: x bf16, reused as vT
  unsigned short* qkv   = (unsigned short*)(ws + (16ull<<20));         // 48MB: qkv bf16
  unsigned short* ob    = (unsigned short*)(ws + (64ull<<20));         // 16MB: o bf16
  unsigned short* wqkvT = (unsigned short*)(ws + (80ull<<20));         // 6MB
  unsigned short* woutT = (unsigned short*)(ws + (86ull<<20));         // 2MB
  unsigned short* vT    = xb;                                          // alias: xb dead after GEMM1

  k_cvt<<<4096, 256, 0, stream>>>(x, xb, (MTOT*DMODEL)/8);
  k_transpose_cvt<<<dim3(96,32), 256, 0, stream>>>(wqkv, wqkvT, DMODEL, NQKV);
  k_transpose_cvt<<<dim3(32,32), 256, 0, stream>>>(wout, woutT, DMODEL, DMODEL);
  k_gemm_bt<1><<<dim3(NQKV/128, MTOT/128), 256, 0, stream>>>(xb, wqkvT, bqkv, qkv, MTOT, NQKV, DMODEL);
  k_norm_rope<<<MTOT, 256, 0, stream>>>(qkv, fcos, fsin, gq, gk);
  k_vT<<<dim3(LSEQ/32, HDIM/32, 16), 256, 0, stream>>>(qkv, vT);
  k_attn<<<dim3(LSEQ/128, 16), 256, 0, stream>>>(qkv, vT, ob);
  k_gemm_bt<0><<<dim3(DMODEL/128, MTOT/128), 256, 0, stream>>>(ob, woutT, bout, out, MTOT, DMODEL, DMODEL);
}